// Round 8
// baseline (454.541 us; speedup 1.0000x reference)
//
#include <hip/hip_runtime.h>

typedef short v8s __attribute__((ext_vector_type(8)));
typedef float v4f __attribute__((ext_vector_type(4)));

// ---- problem constants ----
#define L_SEQ  2048
#define DPROJ  8352
#define CONVD  4224
#define DIN    4096
#define NH     32
#define HD     128
#define NSTATE 64
#define NCHUNK 8
#define CKLEN  256

#define GLOAD_LDS16(gp, lp) \
  __builtin_amdgcn_global_load_lds((const __attribute__((address_space(1))) void*)(gp), \
                                   (__attribute__((address_space(3))) void*)(lp), 16, 0, 0)

__device__ __forceinline__ unsigned short to_bf16(float f) {
  unsigned u = __float_as_uint(f);
  return (unsigned short)((u + 0x7fffu + ((u >> 16) & 1u)) >> 16);
}

// ---------------- fp32 -> bf16 cast, 8 elts/thread ----------------
__global__ void cvt_bf16_kernel(const float* __restrict__ in,
                                unsigned short* __restrict__ out, int n) {
  int i = (blockIdx.x * 256 + threadIdx.x) * 8;
  if (i + 8 <= n) {
    float4 a = *(const float4*)(in + i);
    float4 b = *(const float4*)(in + i + 4);
    v8s r;
    r[0] = (short)to_bf16(a.x); r[1] = (short)to_bf16(a.y);
    r[2] = (short)to_bf16(a.z); r[3] = (short)to_bf16(a.w);
    r[4] = (short)to_bf16(b.x); r[5] = (short)to_bf16(b.y);
    r[6] = (short)to_bf16(b.z); r[7] = (short)to_bf16(b.w);
    *(v8s*)(out + i) = r;
  }
}

// ---------------- 256x256 8-phase bf16 NT GEMM (T2+T3+T4+T5) ----------------
// Generalized: lda/ldb/ldc strides, ncols guard/clamp, split-K via blockIdx.z.
// st_16x32 swizzle BOTH sides: byte ^= ((byte>>7)&7)<<4 (bank-conflict-free,
// verified: SQ_LDS_BANK_CONFLICT = 0 in R6).
// SCHEDB policy (R7): only after LGKM0 (rule #18: stop MFMA hoisting above the
// inline-asm wait) and around VMCNT4/K-tile boundary (protect vmcnt ledger).
// Plain barriers carry NO sched fence so the scheduler may hoist next-phase
// ds_reads/stages into the MFMA region (hazard-audited: reads touch halves no
// stage overwrites this K-tile; register WARs tracked by regalloc).

#define BAR    __builtin_amdgcn_s_barrier()
#define SCHEDB __builtin_amdgcn_sched_barrier(0)
#define LGKM0  asm volatile("s_waitcnt lgkmcnt(0)" ::: "memory")
#define VMCNT4 asm volatile("s_waitcnt vmcnt(4)" ::: "memory")

#define RDA(bu, mh) do { \
  _Pragma("unroll") \
  for (int i = 0; i < 4; ++i) \
    _Pragma("unroll") \
    for (int s = 0; s < 2; ++s) { \
      int row_ = (mh) * 128 + wm * 64 + i * 16 + lrow; \
      int off_ = row_ * 128 + s * 64 + lquad * 16; \
      off_ ^= ((off_ >> 7) & 7) << 4; \
      a8[i][s] = *(const v8s*)((const char*)smem + (bu) * 32768 + off_); \
    } \
} while (0)

#define RDB(bu, nh) do { \
  _Pragma("unroll") \
  for (int j = 0; j < 2; ++j) \
    _Pragma("unroll") \
    for (int s = 0; s < 2; ++s) { \
      int row_ = (nh) * 128 + wn * 32 + j * 16 + lrow; \
      int off_ = row_ * 128 + s * 64 + lquad * 16; \
      off_ ^= ((off_ >> 7) & 7) << 4; \
      b8[nh][j][s] = *(const v8s*)((const char*)smem + 65536 + (bu) * 32768 + off_); \
    } \
} while (0)

#define MM(mh, nh) do { \
  __builtin_amdgcn_s_setprio(1); \
  _Pragma("unroll") \
  for (int i = 0; i < 4; ++i) \
    _Pragma("unroll") \
    for (int j = 0; j < 2; ++j) \
      _Pragma("unroll") \
      for (int s = 0; s < 2; ++s) \
        acc[(mh)*4+i][(nh)*2+j] = __builtin_amdgcn_mfma_f32_16x16x32_bf16( \
            a8[i][s], b8[(nh)][j][s], acc[(mh)*4+i][(nh)*2+j], 0, 0, 0); \
  __builtin_amdgcn_s_setprio(0); \
} while (0)

#define KSTEP(BU, BN_, T1, T2) do { \
  RDA(BU, 0); RDB(BU, 0); \
  stA(BN_, 1, T1); \
  BAR; LGKM0; SCHEDB; \
  MM(0, 0); \
  BAR; \
  RDB(BU, 1); \
  stB(BN_, 1, T1); \
  BAR; LGKM0; SCHEDB; \
  MM(0, 1); \
  BAR; \
  RDA(BU, 1); \
  stA(BU, 0, T2); \
  BAR; LGKM0; SCHEDB; \
  MM(1, 0); \
  BAR; \
  stB(BU, 0, T2); \
  BAR; \
  MM(1, 1); \
  SCHEDB; VMCNT4; SCHEDB; \
  BAR; SCHEDB; \
} while (0)

__global__ __launch_bounds__(512, 2) void gemm_nt_256(
    const unsigned short* __restrict__ A, const unsigned short* __restrict__ B,
    float* __restrict__ C, int lda, int ldb, int ldc, int ncols, int K)
{
  __shared__ unsigned short smem[65536];   // 128 KiB: [A0|A1|B0|B1] 32KB each
  const int m0 = blockIdx.x * 256;
  const int n0 = blockIdx.y * 256;
  // split-K offsets (bz=0 -> no-op)
  A += (size_t)blockIdx.z * K;
  B += (size_t)blockIdx.z * K;
  C += (size_t)blockIdx.z * 2048 * (size_t)ldc;
  const int tid = threadIdx.x;
  const int wave = tid >> 6, lane = tid & 63;
  const int wm = wave >> 2, wn = wave & 3;
  const int lrow = lane & 15, lquad = lane >> 4;
  const int NT = K >> 6;

  v4f acc[8][4] = {};
  v8s a8[4][2];
  v8s b8[2][2][2];

  // stage half h (128 rows x 64 k) of K-tile kt into buffer bu.
  // Linear LDS dest, inverse-swizzled global src (same involution as reads).
  auto stA = [&](int bu, int h, int kt) {
#pragma unroll
    for (int g = 0; g < 2; ++g) {
      int lin = h * 16384 + g * 8192 + tid * 16;           // byte off in region
      int sw = lin ^ (((lin >> 7) & 7) << 4);
      int row = sw >> 7;                                   // region row 0..255
      const unsigned short* src = A + (size_t)(m0 + row) * lda + kt * 64 + ((sw & 127) >> 1);
      GLOAD_LDS16(src, smem + bu * 16384 + h * 8192 + g * 4096 + wave * 512);
    }
  };
  auto stB = [&](int bu, int h, int kt) {
#pragma unroll
    for (int g = 0; g < 2; ++g) {
      int lin = h * 16384 + g * 8192 + tid * 16;
      int sw = lin ^ (((lin >> 7) & 7) << 4);
      int brow = n0 + (sw >> 7);
      if (brow >= ncols) brow = ncols - 1;                 // N-tail clamp
      const unsigned short* src = B + (size_t)brow * ldb + kt * 64 + ((sw & 127) >> 1);
      GLOAD_LDS16(src, smem + 32768 + bu * 16384 + h * 8192 + g * 4096 + wave * 512);
    }
  };

  // prologue: tile0 complete + A0,B0 of tile1; drain tile0 (newest 4 stay)
  stA(0, 0, 0); stA(0, 1, 0); stB(0, 0, 0); stB(0, 1, 0);
  stA(1, 0, 1); stB(1, 0, 1);
  SCHEDB; VMCNT4; SCHEDB; BAR; SCHEDB;

#pragma unroll 1
  for (int tt = 0; tt < NT; tt += 2) {
    {
      int t1 = tt + 1;                                   // < NT always (NT even)
      int t2 = (tt + 2 < NT) ? tt + 2 : NT - 1;
      KSTEP(0, 1, t1, t2);
    }
    {
      int t1 = (tt + 2 < NT) ? tt + 2 : NT - 1;
      int t2 = (tt + 3 < NT) ? tt + 3 : NT - 1;
      KSTEP(1, 0, t1, t2);
    }
  }

#pragma unroll
  for (int mh = 0; mh < 2; ++mh)
#pragma unroll
    for (int i = 0; i < 4; ++i) {
      int grow = m0 + mh * 128 + wm * 64 + i * 16 + lquad * 4;
#pragma unroll
      for (int nh = 0; nh < 2; ++nh)
#pragma unroll
        for (int j = 0; j < 2; ++j) {
          int gcol = n0 + nh * 128 + wn * 32 + j * 16 + lrow;
          if (gcol < ncols) {
#pragma unroll
            for (int r = 0; r < 4; ++r)
              C[(size_t)(grow + r) * ldc + gcol] = acc[mh * 4 + i][nh * 2 + j][r];
          }
        }
    }
}

// ---------------- split-K reduce: out = p0+p1+p2+p3 (fp32, float4) --------
__global__ __launch_bounds__(256) void reduce_k4_kernel(
    const float* __restrict__ p, float* __restrict__ out, int n)
{
  const int S = 4194304;
  int i = (blockIdx.x * 256 + threadIdx.x) * 4;
  if (i + 4 <= n) {
    float4 a = *(const float4*)(p + i);
    float4 b = *(const float4*)(p + S + i);
    float4 c = *(const float4*)(p + 2 * S + i);
    float4 d = *(const float4*)(p + 3 * S + i);
    float4 o;
    o.x = a.x + b.x + c.x + d.x;
    o.y = a.y + b.y + c.y + d.y;
    o.z = a.z + b.z + c.z + d.z;
    o.w = a.w + b.w + c.w + d.w;
    *(float4*)(out + i) = o;
  }
}

// ---------------- bf16 NT GEMM 64x128 tail (Ncols/ldc, clamp+guard) -------
// B and C pre-offset to first tail column; ldc = full C row stride.
__global__ __launch_bounds__(256) void gemm_nt_64tail(
    const unsigned short* __restrict__ A, const unsigned short* __restrict__ B,
    float* __restrict__ C, int Ncols, int ldc, int K)
{
  __shared__ unsigned short As[64 * 32];
  __shared__ unsigned short Bs[128 * 32];
  const int m0 = blockIdx.x * 64;
  const int n0 = blockIdx.y * 128;
  const int tid = threadIdx.x;
  const int wave = tid >> 6, lane = tid & 63;
  const int wm = (wave & 1) * 32, wn = (wave >> 1) * 64;
  const int lrow = lane & 15, lquad = lane >> 4;

  v4f acc[2][4] = {};

  for (int k0 = 0; k0 < K; k0 += 32) {
    __syncthreads();
    {
      int e = wave * 64 + lane;
      int row = e >> 2;
      int kq = (e & 3) * 8;
      const unsigned short* ap = A + (size_t)(m0 + row) * K + k0 + kq;
      GLOAD_LDS16(ap, As + wave * 512);
    }
#pragma unroll
    for (int r = 0; r < 2; ++r) {
      int e = wave * 128 + r * 64 + lane;
      int row = e >> 2;
      int kq = (e & 3) * 8;
      int br = n0 + row; if (br >= Ncols) br = Ncols - 1;
      const unsigned short* bp = B + (size_t)br * K + k0 + kq;
      GLOAD_LDS16(bp, Bs + wave * 1024 + r * 512);
    }
    __syncthreads();
    v8s af[2], bfr[4];
#pragma unroll
    for (int i = 0; i < 2; ++i)
      af[i] = *(const v8s*)&As[(wm + i * 16 + lrow) * 32 + lquad * 8];
#pragma unroll
    for (int j = 0; j < 4; ++j)
      bfr[j] = *(const v8s*)&Bs[(wn + j * 16 + lrow) * 32 + lquad * 8];
#pragma unroll
    for (int i = 0; i < 2; ++i)
#pragma unroll
      for (int j = 0; j < 4; ++j)
        acc[i][j] = __builtin_amdgcn_mfma_f32_16x16x32_bf16(af[i], bfr[j], acc[i][j], 0, 0, 0);
  }

#pragma unroll
  for (int i = 0; i < 2; ++i) {
    int grow = m0 + wm + i * 16 + lquad * 4;
#pragma unroll
    for (int j = 0; j < 4; ++j) {
      int gcol = n0 + wn + j * 16 + lrow;
      if (gcol < Ncols) {
#pragma unroll
        for (int r = 0; r < 4; ++r)
          C[(size_t)(grow + r) * ldc + gcol] = acc[i][j][r];
      }
    }
  }
}

// ---------------- causal depthwise conv1d(4) + SiLU, LDS-tiled ------------
__global__ __launch_bounds__(256) void conv_silu_kernel(
    const float* __restrict__ zx, const float* __restrict__ cw,
    const float* __restrict__ cb, float* __restrict__ out)
{
  const int l0 = blockIdx.x * 32, c0 = blockIdx.y * 128;
  const int tid = threadIdx.x;
  __shared__ float zs[35][128];
  __shared__ float cwl[4][128];
  __shared__ float cbl[128];
  for (int e = tid; e < 35 * 128; e += 256) {
    int k = e >> 7, cc = e & 127;
    int l = l0 + k - 3;
    zs[k][cc] = (l >= 0) ? zx[(size_t)l * DPROJ + DIN + c0 + cc] : 0.f;
  }
  for (int e = tid; e < 512; e += 256)
    cwl[e & 3][e >> 2] = cw[c0 * 4 + e];
  if (tid < 128) cbl[tid] = cb[c0 + tid];
  __syncthreads();
#pragma unroll
  for (int i = 0; i < 16; ++i) {
    int idx = i * 256 + tid;
    int ll = idx >> 7, cc = idx & 127;
    float acc = cbl[cc];
#pragma unroll
    for (int j = 0; j < 4; ++j)
      acc += zs[ll + j][cc] * cwl[j][cc];
    out[(size_t)(l0 + ll) * CONVD + c0 + cc] = acc / (1.f + __expf(-acc));
  }
}

// ---------------- dt = softplus(raw + bias) ----------------
__global__ void dt_kernel(const float* __restrict__ zx,
                          const float* __restrict__ dtb,
                          float* __restrict__ dt)
{
  int e = blockIdx.x * 256 + threadIdx.x;
  int l = e >> 5, h = e & 31;
  float v = zx[(size_t)l * DPROJ + (DPROJ - NH) + h] + dtb[h];
  dt[e] = (v > 20.f) ? v : log1pf(__expf(v));
}

// ---------------- per-(head,chunk) inclusive cumsum of A*dt ----------------
__global__ void acum_kernel(const float* __restrict__ dt,
                            const float* __restrict__ alog,
                            float* __restrict__ acum)
{
  int h = blockIdx.x & 31, c = blockIdx.x >> 5;
  int t = threadIdx.x;
  int l = c * CKLEN + t;
  float A = -__expf(alog[h]);
  __shared__ float s[256];
  s[t] = A * dt[l * NH + h];
  __syncthreads();
  for (int off = 1; off < 256; off <<= 1) {
    float add = (t >= off) ? s[t - off] : 0.f;
    __syncthreads();
    s[t] += add;
    __syncthreads();
  }
  acum[h * L_SEQ + l] = s[t];
}

// ---------------- prep: Xd (bf16 [c][h][p][t]), Btw (bf16 [c][h][n][t]),
//                  Cbf (bf16 [c][l][n], head-independent) ----------
__global__ __launch_bounds__(256) void prep_kernel(
    const float* __restrict__ xbc, const float* __restrict__ dt,
    const float* __restrict__ acum, unsigned short* __restrict__ Xd,
    unsigned short* __restrict__ Btw, unsigned short* __restrict__ Cbf)
{
  const int h = blockIdx.x & 31, c = blockIdx.x >> 5;
  const int tid = threadIdx.x;
  __shared__ float Ac[256], Dt[256], Wd[256];
  __shared__ float Xs[32][129];
  __shared__ float Bs2[32][65];
  int l = c * CKLEN + tid;
  float a = acum[h * L_SEQ + l];
  Ac[tid] = a;
  Dt[tid] = dt[l * NH + h];
  __syncthreads();
  float alast = Ac[255];
  Wd[tid] = __expf(fminf(alast - a, 0.f));
  __syncthreads();
  unsigned short* XdB = Xd + (size_t)(c * NH + h) * (HD * CKLEN);
  unsigned short* BtB = Btw + (size_t)(c * NH + h) * (NSTATE * CKLEN);
  for (int t0 = 0; t0 < CKLEN; t0 += 32) {
    for (int e = tid; e < 32 * 128; e += 256) {
      int tt = e >> 7, pp = e & 127;
      Xs[tt][pp] = xbc[(size_t)(c * CKLEN + t0 + tt) * CONVD + h * HD + pp];
    }
    for (int e = tid; e < 32 * 64; e += 256) {
      int tt = e >> 6, nn = e & 63;
      Bs2[tt][nn] = xbc[(size_t)(c * CKLEN + t0 + tt) * CONVD + DIN + nn];
    }
    __syncthreads();
    {
      int p = tid >> 1, th = (tid & 1) * 16;
      v8s r0, r1;
#pragma unroll
      for (int k = 0; k < 8; ++k) {
        r0[k] = (short)to_bf16(Xs[th + k][p] * Dt[t0 + th + k]);
        r1[k] = (short)to_bf16(Xs[th + 8 + k][p] * Dt[t0 + th + 8 + k]);
      }
      *(v8s*)&XdB[p * CKLEN + t0 + th] = r0;
      *(v8s*)&XdB[p * CKLEN + t0 + th + 8] = r1;
    }
    {
      int n = tid >> 2, tq = (tid & 3) * 8;
      v8s r;
#pragma unroll
      for (int k = 0; k < 8; ++k)
        r[k] = (short)to_bf16(Bs2[tq + k][n] * Wd[t0 + tq + k]);
      *(v8s*)&BtB[n * CKLEN + t0 + tq] = r;
    }
    __syncthreads();
  }
  if (h == 0) {
    for (int e = tid; e < CKLEN * NSTATE; e += 256) {
      int ll = e >> 6, nn = e & 63;
      Cbf[(size_t)c * (CKLEN * NSTATE) + e] =
          to_bf16(xbc[(size_t)(c * CKLEN + ll) * CONVD + DIN + NSTATE + nn]);
    }
  }
}

// ---------------- G[c][l][s] = C_l . B_s (fp32, per chunk) ----------------
__global__ __launch_bounds__(256) void g_kernel(const float* __restrict__ xbc,
                                                float* __restrict__ G)
{
  int c = blockIdx.z;
  int l0 = blockIdx.y * 64, s0 = blockIdx.x * 64;
  __shared__ float Cs[64][65];
  __shared__ float Bs[64][65];
  int tid = threadIdx.x;
  for (int e = tid; e < 64 * 64; e += 256) {
    int r = e >> 6, k = e & 63;
    Cs[r][k] = xbc[(size_t)(c * CKLEN + l0 + r) * CONVD + DIN + NSTATE + k];
    Bs[r][k] = xbc[(size_t)(c * CKLEN + s0 + r) * CONVD + DIN + k];
  }
  __syncthreads();
  int tx = tid & 15, ty = tid >> 4;
  float acc[4][4] = {};
  for (int k = 0; k < 64; ++k) {
    float a[4], b[4];
#pragma unroll
    for (int i = 0; i < 4; ++i) a[i] = Cs[ty * 4 + i][k];
#pragma unroll
    for (int j = 0; j < 4; ++j) b[j] = Bs[tx * 4 + j][k];
#pragma unroll
    for (int i = 0; i < 4; ++i)
#pragma unroll
      for (int j = 0; j < 4; ++j) acc[i][j] += a[i] * b[j];
  }
  for (int i = 0; i < 4; ++i)
    for (int j = 0; j < 4; ++j)
      G[((size_t)c * CKLEN + l0 + ty * 4 + i) * CKLEN + s0 + tx * 4 + j] = acc[i][j];
}

// ---------------- Gexp v2: G tile in LDS once, loop all 32 heads ----------
__global__ __launch_bounds__(256) void gexp_kernel_v2(
    const float* __restrict__ G, const float* __restrict__ acum,
    unsigned short* __restrict__ Gexp)
{
  const int b = blockIdx.x;
  const int si = b & 7, li = (b >> 3) & 3, c = b >> 5;
  const int l0 = li * 64, s0 = si * 32;
  const int tid = threadIdx.x;
  const int r = tid >> 2, sc = (tid & 3) * 8;

  if (s0 >= l0 + 64) {
    v8s z = {};
    for (int h = 0; h < NH; ++h)
      *(v8s*)&Gexp[(size_t)(c * NH + h) * 65536 + (size_t)(l0 + r) * 256 + s0 + sc] = z;
    return;
  }

  __shared__ float Gs[64 * 32];
  __shared__ float Acl[32][64];
  __shared__ float Acs[32][32];
  for (int e = tid; e < 2048; e += 256) {
    int rr = e >> 5, cc = e & 31;
    Gs[e] = G[(size_t)c * 65536 + (size_t)(l0 + rr) * 256 + s0 + cc];
  }
  for (int e = tid; e < 2048; e += 256) {
    int hh = e >> 6, rr = e & 63;
    Acl[hh][rr] = acum[hh * L_SEQ + c * CKLEN + l0 + rr];
  }
  for (int e = tid; e < 1024; e += 256) {
    int hh = e >> 5, ss = e & 31;
    Acs[hh][ss] = acum[hh * L_SEQ + c * CKLEN + s0 + ss];
  }
  __syncthreads();

  float g8[8];
#pragma unroll
  for (int k = 0; k < 8; ++k) g8[k] = Gs[r * 32 + sc + k];

  for (int h = 0; h < NH; ++h) {
    float al = Acl[h][r];
    v8s o;
#pragma unroll
    for (int k = 0; k < 8; ++k) {
      int s = s0 + sc + k;
      float m = 0.f;
      if (s <= l0 + r) m = g8[k] * __expf(fminf(al - Acs[h][sc + k], 0.f));
      o[k] = (short)to_bf16(m);
    }
    *(v8s*)&Gexp[(size_t)(c * NH + h) * 65536 + (size_t)(l0 + r) * 256 + s0 + sc] = o;
  }
}

// ---------------- chunk states: st[p][n] = Xd[p][:] . Btw[n][:] -----------
__global__ __launch_bounds__(256) void states_kernel_v2(
    const unsigned short* __restrict__ Xd, const unsigned short* __restrict__ Btw,
    float* __restrict__ st)
{
  const int h = blockIdx.x & 31, c = blockIdx.x >> 5;
  const int tid = threadIdx.x;
  const int wave = tid >> 6, lane = tid & 63;
  const int wm = (wave & 1) * 64, wn = (wave >> 1) * 32;
  const int lrow = lane & 15, lquad = lane >> 4;

  __shared__ unsigned short As[128 * 32];
  __shared__ unsigned short Bs[64 * 32];
  const unsigned short* Ab = Xd + (size_t)(c * NH + h) * (HD * CKLEN);
  const unsigned short* Bb = Btw + (size_t)(c * NH + h) * (NSTATE * CKLEN);

  v4f acc[4][2] = {};

  for (int k0 = 0; k0 < CKLEN; k0 += 32) {
    __syncthreads();
#pragma unroll
    for (int r = 0; r < 2; ++r) {
      int e = wave * 128 + r * 64 + lane;
      int row = e >> 2, kq = (e & 3) * 8;
      GLOAD_LDS16(Ab + (size_t)row * CKLEN + k0 + kq, As + wave * 1024 + r * 512);
    }
    {
      int e = wave * 64 + lane;
      int row = e >> 2, kq = (e & 3) * 8;
      GLOAD_LDS16(Bb + (size_t)row * CKLEN + k0 + kq, Bs + wave * 512);
    }
    __syncthreads();
    v8s af[4], bfr[2];
#pragma unroll
    for (int i = 0; i < 4; ++i)
      af[i] = *(const v8s*)&As[(wm + i * 16 + lrow) * 32 + lquad * 8];
#pragma unroll
    for (int j = 0; j < 2; ++j)
      bfr[j] = *(const v8s*)&Bs[(wn + j * 16 + lrow) * 32 + lquad * 8];
#pragma unroll
    for (int i = 0; i < 4; ++i)
#pragma unroll
      for (int j = 0; j < 2; ++j)
        acc[i][j] = __builtin_amdgcn_mfma_f32_16x16x32_bf16(af[i], bfr[j], acc[i][j], 0, 0, 0);
  }

  float* outp = st + (size_t)(c * NH + h) * (HD * NSTATE);
#pragma unroll
  for (int i = 0; i < 4; ++i) {
    int p0 = wm + i * 16 + lquad * 4;
#pragma unroll
    for (int j = 0; j < 2; ++j) {
      int n = wn + j * 16 + lrow;
#pragma unroll
      for (int r = 0; r < 4; ++r)
        outp[(size_t)(p0 + r) * NSTATE + n] = acc[i][j][r];
    }
  }
}

// ---------------- inter-chunk scan -> bf16 sp ----------------
__global__ void scan_kernel(const float* __restrict__ acum,
                            const float* __restrict__ st,
                            unsigned short* __restrict__ spbf)
{
  int e = blockIdx.x * 256 + threadIdx.x;
  int h = e >> 13;
  float running = 0.f;
#pragma unroll
  for (int c = 0; c < NCHUNK; ++c) {
    spbf[(size_t)c * 262144 + e] = to_bf16(running);
    float dec = __expf(fminf(acum[h * L_SEQ + c * CKLEN + 255], 0.f));
    running = running * dec + st[(size_t)c * 262144 + e];
  }
}

// ---------------- Y: acc = Cbf @ sp^T; acc *= exp(Ac[l]); acc += Gexp @ Xd^T;
//                  Y = acc + D*xs ----------------
__global__ __launch_bounds__(256) void y_kernel_v2(
    const unsigned short* __restrict__ Gexp, const unsigned short* __restrict__ Xd,
    const unsigned short* __restrict__ Cbf, const unsigned short* __restrict__ spbf,
    const float* __restrict__ xbc, const float* __restrict__ acum,
    const float* __restrict__ Dp, float* __restrict__ Y)
{
  const int b = blockIdx.x, h = blockIdx.y, c = blockIdx.z;
  const int tid = threadIdx.x;
  const int wave = tid >> 6, lane = tid & 63;
  const int wm = wave * 32;
  const int lrow = lane & 15, lquad = lane >> 4;

  __shared__ unsigned short As[128 * 32];
  __shared__ unsigned short Bs[128 * 32];

  v4f acc[2][8] = {};

  const unsigned short* Ca = Cbf + (size_t)c * (CKLEN * NSTATE) + (size_t)b * 128 * NSTATE;
  const unsigned short* Sb = spbf + (size_t)(c * NH + h) * (HD * NSTATE);
  for (int n0 = 0; n0 < NSTATE; n0 += 32) {
    __syncthreads();
#pragma unroll
    for (int r = 0; r < 2; ++r) {
      int e = wave * 128 + r * 64 + lane;
      int row = e >> 2, kq = (e & 3) * 8;
      GLOAD_LDS16(Ca + (size_t)row * NSTATE + n0 + kq, As + wave * 1024 + r * 512);
      GLOAD_LDS16(Sb + (size_t)row * NSTATE + n0 + kq, Bs + wave * 1024 + r * 512);
    }
    __syncthreads();
    v8s af[2], bfr[8];
#pragma unroll
    for (int i = 0; i < 2; ++i)
      af[i] = *(const v8s*)&As[(wm + i * 16 + lrow) * 32 + lquad * 8];
#pragma unroll
    for (int j = 0; j < 8; ++j)
      bfr[j] = *(const v8s*)&Bs[(j * 16 + lrow) * 32 + lquad * 8];
#pragma unroll
    for (int i = 0; i < 2; ++i)
#pragma unroll
      for (int j = 0; j < 8; ++j)
        acc[i][j] = __builtin_amdgcn_mfma_f32_16x16x32_bf16(af[i], bfr[j], acc[i][j], 0, 0, 0);
  }

#pragma unroll
  for (int i = 0; i < 2; ++i) {
#pragma unroll
    for (int r = 0; r < 4; ++r) {
      int Lg = c * CKLEN + b * 128 + wm + i * 16 + lquad * 4 + r;
      float eA = __expf(fminf(acum[h * L_SEQ + Lg], 0.f));
#pragma unroll
      for (int j = 0; j < 8; ++j) acc[i][j][r] *= eA;
    }
  }

  const unsigned short* Ga = Gexp + (size_t)(c * NH + h) * (CKLEN * CKLEN)
                           + (size_t)b * 128 * CKLEN;
  const unsigned short* Xb = Xd + (size_t)(c * NH + h) * (HD * CKLEN);

  const int smax = (b + 1) * 128;
  for (int s0 = 0; s0 < smax; s0 += 32) {
    __syncthreads();
#pragma unroll
    for (int r = 0; r < 2; ++r) {
      int e = wave * 128 + r * 64 + lane;
      int row = e >> 2, kq = (e & 3) * 8;
      GLOAD_LDS16(Ga + (size_t)row * CKLEN + s0 + kq, As + wave * 1024 + r * 512);
      GLOAD_LDS16(Xb + (size_t)row * CKLEN + s0 + kq, Bs + wave * 1024 + r * 512);
    }
    __syncthreads();
    if (s0 <= b * 128 + wm + 31) {
      v8s af[2], bfr[8];
#pragma unroll
      for (int i = 0; i < 2; ++i)
        af[i] = *(const v8s*)&As[(wm + i * 16 + lrow) * 32 + lquad * 8];
#pragma unroll
      for (int j = 0; j < 8; ++j)
        bfr[j] = *(const v8s*)&Bs[(j * 16 + lrow) * 32 + lquad * 8];
#pragma unroll
      for (int i = 0; i < 2; ++i)
#pragma unroll
        for (int j = 0; j < 8; ++j)
          acc[i][j] = __builtin_amdgcn_mfma_f32_16x16x32_bf16(af[i], bfr[j], acc[i][j], 0, 0, 0);
    }
  }

  const float Dh = Dp[h];
#pragma unroll
  for (int i = 0; i < 2; ++i) {
#pragma unroll
    for (int j = 0; j < 8; ++j) {
      int p = j * 16 + lrow;
#pragma unroll
      for (int r = 0; r < 4; ++r) {
        int Lg = c * CKLEN + b * 128 + wm + i * 16 + lquad * 4 + r;
        float xs = xbc[(size_t)Lg * CONVD + h * HD + p];
        Y[(size_t)Lg * DIN + h * HD + p] = acc[i][j][r] + Dh * xs;
      }
    }
  }
}

// ---------------- gated RMSNorm -> bf16 ----------------
__global__ __launch_bounds__(256) void norm_gate_kernel(const float* __restrict__ Y,
                                                        const float* __restrict__ zx,
                                                        const float* __restrict__ nw,
                                                        unsigned short* __restrict__ gbf)
{
  int l = blockIdx.x;
  int t = threadIdx.x;
  float g[16];
  float ss = 0.f;
#pragma unroll
  for (int i = 0; i < 16; ++i) {
    int idx = i * 256 + t;
    float z = zx[(size_t)l * DPROJ + idx];
    float y = Y[(size_t)l * DIN + idx];
    float gv = y * (z / (1.f + __expf(-z)));
    g[i] = gv;
    ss += gv * gv;
  }
#pragma unroll
  for (int off = 32; off > 0; off >>= 1) ss += __shfl_down(ss, off);
  __shared__ float red[4];
  if ((t & 63) == 0) red[t >> 6] = ss;
  __syncthreads();
  float total = red[0] + red[1] + red[2] + red[3];
  float scale = rsqrtf(total / (float)DIN + 1e-5f);
#pragma unroll
  for (int i = 0; i < 16; ++i) {
    int idx = i * 256 + t;
    gbf[(size_t)l * DIN + idx] = to_bf16(g[i] * scale * nw[idx]);
  }
}

// ---------------- launch ----------------
extern "C" void kernel_launch(void* const* d_in, const int* in_sizes, int n_in,
                              void* d_out, int out_size, void* d_ws, size_t ws_size,
                              hipStream_t stream) {
  const float* x    = (const float*)d_in[0];
  const float* w1   = (const float*)d_in[1];
  const float* cw   = (const float*)d_in[2];
  const float* cb   = (const float*)d_in[3];
  const float* dtb  = (const float*)d_in[4];
  const float* alog = (const float*)d_in[5];
  const float* Dp   = (const float*)d_in[6];
  const float* nw   = (const float*)d_in[7];
  const float* w2   = (const float*)d_in[8];
  float* out = (float*)d_out;
  float* ws  = (float*)d_ws;

  // scratch layout (float units). Gexp/Btw overlay xbf/w1bf (dead after gemm1).
  // zx region is reused for gemm2 split-K partials (zx dead after norm_gate).
  unsigned short* xbf  = (unsigned short*)(ws + 0);          // 2048*2048 bf16
  unsigned short* w1bf = (unsigned short*)(ws + 2097152);    // 8352*2048 bf16
  unsigned short* Gexp = (unsigned short*)(ws + 0);          // 8*32*256*256 bf16 (post-gemm1)
  unsigned short* Btw  = (unsigned short*)(ws + 8388608);    // 8*32*64*256 bf16 (post-gemm1)
  unsigned short* w2bf = (unsigned short*)(ws + 10649600);   // 2048*4096 bf16
  float* zx   = ws + 14843904;   // 2048*8352
  float* part = ws + 14843904;   // 4*2048*2048 fp32 partials (post-norm_gate)
  float* xbc  = ws + 31948800;   // 2048*4224
  float* dt   = ws + 40599552;   // 2048*32
  float* acum = ws + 40665088;   // 32*2048
  float* G    = ws + 40730624;   // 8*256*256 fp32
  float* st   = ws + 41254912;   // 8*32*128*64 fp32
  float* Y    = ws + 43352064;   // 2048*4096
  unsigned short* gbf  = (unsigned short*)(ws + 51740672);   // 2048*4096 bf16
  unsigned short* Xd   = (unsigned short*)(ws + 53837824);   // 8*32*128*256 bf16
  unsigned short* Cbf  = (unsigned short*)(ws + 58032128);   // 8*256*64 bf16
  unsigned short* spbf = (unsigned short*)(ws + 58097664);   // 8*32*128*64 bf16

  cvt_bf16_kernel<<<4194304 / 2048, 256, 0, stream>>>(x, xbf, 4194304);
  cvt_bf16_kernel<<<17104896 / 2048, 256, 0, stream>>>(w1, w1bf, 17104896);
  cvt_bf16_kernel<<<8388608 / 2048, 256, 0, stream>>>(w2, w2bf, 8388608);

  // zxbcdt = x @ in_proj_w^T   (M=2048, N=8352, K=2048)
  // main: 256x256 8-phase on cols 0..8191 (exactly 256 blocks, 1 round)
  gemm_nt_256<<<dim3(8, 32, 1), 512, 0, stream>>>(
      xbf, w1bf, zx, 2048, 2048, 8352, 8352, 2048);
  // tail: cols 8192..8351 (160 cols) via guarded 64x128 kernel (64 blocks)
  gemm_nt_64tail<<<dim3(32, 2), 256, 0, stream>>>(
      xbf, w1bf + (size_t)8192 * 2048, zx + 8192, 160, 8352, 2048);

  conv_silu_kernel<<<dim3(64, 33), 256, 0, stream>>>(zx, cw, cb, xbc);
  dt_kernel<<<(L_SEQ * NH) / 256, 256, 0, stream>>>(zx, dtb, dt);
  acum_kernel<<<NCHUNK * NH, 256, 0, stream>>>(dt, alog, acum);

  prep_kernel<<<NCHUNK * NH, 256, 0, stream>>>(xbc, dt, acum, Xd, Btw, Cbf);
  g_kernel<<<dim3(4, 4, NCHUNK), 256, 0, stream>>>(xbc, G);
  gexp_kernel_v2<<<256, 256, 0, stream>>>(G, acum, Gexp);

  states_kernel_v2<<<NCHUNK * NH, 256, 0, stream>>>(Xd, Btw, st);
  scan_kernel<<<262144 / 256, 256, 0, stream>>>(acum, st, spbf);
  y_kernel_v2<<<dim3(2, NH, NCHUNK), 256, 0, stream>>>(Gexp, Xd, Cbf, spbf, xbc, acum, Dp, Y);

  norm_gate_kernel<<<L_SEQ, 256, 0, stream>>>(Y, zx, nw, gbf);

  // out = g @ out_proj_w^T (M=2048, N=2048, K=4096): split-K x4 through the
  // 256x256 8-phase kernel (grid 8x8x4 = 256 blocks, K=1024/split), fp32
  // partials in the dead zx region, then a float4 reduce.
  gemm_nt_256<<<dim3(8, 8, 4), 512, 0, stream>>>(
      gbf, w2bf, part, 4096, 4096, 2048, 2048, 1024);
  reduce_k4_kernel<<<4194304 / 1024, 256, 0, stream>>>(part, out, 4194304);
}

// Round 11
// 426.285 us; speedup vs baseline: 1.0663x; 1.0663x over previous
//
#include <hip/hip_runtime.h>

typedef short v8s __attribute__((ext_vector_type(8)));
typedef float v4f __attribute__((ext_vector_type(4)));

// ---- problem constants ----
#define L_SEQ  2048
#define DPROJ  8352
#define CONVD  4224
#define DIN    4096
#define NH     32
#define HD     128
#define NSTATE 64
#define NCHUNK 8
#define CKLEN  256

#define GLOAD_LDS16(gp, lp) \
  __builtin_amdgcn_global_load_lds((const __attribute__((address_space(1))) void*)(gp), \
                                   (__attribute__((address_space(3))) void*)(lp), 16, 0, 0)

__device__ __forceinline__ unsigned short to_bf16(float f) {
  unsigned u = __float_as_uint(f);
  return (unsigned short)((u + 0x7fffu + ((u >> 16) & 1u)) >> 16);
}

// ---------------- fp32 -> bf16 cast, 8 elts/thread ----------------
__global__ void cvt_bf16_kernel(const float* __restrict__ in,
                                unsigned short* __restrict__ out, int n) {
  int i = (blockIdx.x * 256 + threadIdx.x) * 8;
  if (i + 8 <= n) {
    float4 a = *(const float4*)(in + i);
    float4 b = *(const float4*)(in + i + 4);
    v8s r;
    r[0] = (short)to_bf16(a.x); r[1] = (short)to_bf16(a.y);
    r[2] = (short)to_bf16(a.z); r[3] = (short)to_bf16(a.w);
    r[4] = (short)to_bf16(b.x); r[5] = (short)to_bf16(b.y);
    r[6] = (short)to_bf16(b.z); r[7] = (short)to_bf16(b.w);
    *(v8s*)(out + i) = r;
  }
}

// ---------------- 256x256 8-phase bf16 NT GEMM (T1+T2+T3+T4+T5) -------------
// Generalized: lda/ldb/ldc strides, ncols guard/clamp, split-K via blockIdx.z.
// st_16x32 swizzle BOTH sides: byte ^= ((byte>>7)&7)<<4 (SQ_LDS_BANK_CONFLICT
// = 0, verified R6). SCHEDB policy: after LGKM0 (rule #18) and around VMCNT4.
// T1 XCD-aware block swizzle (m204 bijective; requires nwg%8==0 — holds:
// gemm1 8x32=256, gemm2 8x8=64/slice). XCD k gets a contiguous by-range so
// B-panels are reused within one L2 instead of fetched into 8.

#define BAR    __builtin_amdgcn_s_barrier()
#define SCHEDB __builtin_amdgcn_sched_barrier(0)
#define LGKM0  asm volatile("s_waitcnt lgkmcnt(0)" ::: "memory")
#define VMCNT4 asm volatile("s_waitcnt vmcnt(4)" ::: "memory")

#define RDA(bu, mh) do { \
  _Pragma("unroll") \
  for (int i = 0; i < 4; ++i) \
    _Pragma("unroll") \
    for (int s = 0; s < 2; ++s) { \
      int row_ = (mh) * 128 + wm * 64 + i * 16 + lrow; \
      int off_ = row_ * 128 + s * 64 + lquad * 16; \
      off_ ^= ((off_ >> 7) & 7) << 4; \
      a8[i][s] = *(const v8s*)((const char*)smem + (bu) * 32768 + off_); \
    } \
} while (0)

#define RDB(bu, nh) do { \
  _Pragma("unroll") \
  for (int j = 0; j < 2; ++j) \
    _Pragma("unroll") \
    for (int s = 0; s < 2; ++s) { \
      int row_ = (nh) * 128 + wn * 32 + j * 16 + lrow; \
      int off_ = row_ * 128 + s * 64 + lquad * 16; \
      off_ ^= ((off_ >> 7) & 7) << 4; \
      b8[nh][j][s] = *(const v8s*)((const char*)smem + 65536 + (bu) * 32768 + off_); \
    } \
} while (0)

#define MM(mh, nh) do { \
  __builtin_amdgcn_s_setprio(1); \
  _Pragma("unroll") \
  for (int i = 0; i < 4; ++i) \
    _Pragma("unroll") \
    for (int j = 0; j < 2; ++j) \
      _Pragma("unroll") \
      for (int s = 0; s < 2; ++s) \
        acc[(mh)*4+i][(nh)*2+j] = __builtin_amdgcn_mfma_f32_16x16x32_bf16( \
            a8[i][s], b8[(nh)][j][s], acc[(mh)*4+i][(nh)*2+j], 0, 0, 0); \
  __builtin_amdgcn_s_setprio(0); \
} while (0)

#define KSTEP(BU, BN_, T1, T2) do { \
  RDA(BU, 0); RDB(BU, 0); \
  stA(BN_, 1, T1); \
  BAR; LGKM0; SCHEDB; \
  MM(0, 0); \
  BAR; \
  RDB(BU, 1); \
  stB(BN_, 1, T1); \
  BAR; LGKM0; SCHEDB; \
  MM(0, 1); \
  BAR; \
  RDA(BU, 1); \
  stA(BU, 0, T2); \
  BAR; LGKM0; SCHEDB; \
  MM(1, 0); \
  BAR; \
  stB(BU, 0, T2); \
  BAR; \
  MM(1, 1); \
  SCHEDB; VMCNT4; SCHEDB; \
  BAR; SCHEDB; \
} while (0)

__global__ __launch_bounds__(512, 2) void gemm_nt_256(
    const unsigned short* __restrict__ A, const unsigned short* __restrict__ B,
    float* __restrict__ C, int lda, int ldb, int ldc, int ncols, int K)
{
  __shared__ unsigned short smem[65536];   // 128 KiB: [A0|A1|B0|B1] 32KB each
  // T1 XCD swizzle (bijective, nwg%8==0): XCD k <- contiguous by-chunk.
  const int nwgx = gridDim.x;
  const int nwg  = nwgx * gridDim.y;
  const int lin  = blockIdx.x + nwgx * blockIdx.y;
  const int q    = nwg >> 3;
  const int swz  = (lin & 7) * q + (lin >> 3);
  const int m0 = (swz % nwgx) * 256;
  const int n0 = (swz / nwgx) * 256;
  // split-K offsets (bz=0 -> no-op)
  A += (size_t)blockIdx.z * K;
  B += (size_t)blockIdx.z * K;
  C += (size_t)blockIdx.z * 2048 * (size_t)ldc;
  const int tid = threadIdx.x;
  const int wave = tid >> 6, lane = tid & 63;
  const int wm = wave >> 2, wn = wave & 3;
  const int lrow = lane & 15, lquad = lane >> 4;
  const int NT = K >> 6;

  v4f acc[8][4] = {};
  v8s a8[4][2];
  v8s b8[2][2][2];

  // stage half h (128 rows x 64 k) of K-tile kt into buffer bu.
  // Linear LDS dest, inverse-swizzled global src (same involution as reads).
  auto stA = [&](int bu, int h, int kt) {
#pragma unroll
    for (int g = 0; g < 2; ++g) {
      int lin2 = h * 16384 + g * 8192 + tid * 16;          // byte off in region
      int sw = lin2 ^ (((lin2 >> 7) & 7) << 4);
      int row = sw >> 7;                                   // region row 0..255
      const unsigned short* src = A + (size_t)(m0 + row) * lda + kt * 64 + ((sw & 127) >> 1);
      GLOAD_LDS16(src, smem + bu * 16384 + h * 8192 + g * 4096 + wave * 512);
    }
  };
  auto stB = [&](int bu, int h, int kt) {
#pragma unroll
    for (int g = 0; g < 2; ++g) {
      int lin2 = h * 16384 + g * 8192 + tid * 16;
      int sw = lin2 ^ (((lin2 >> 7) & 7) << 4);
      int brow = n0 + (sw >> 7);
      if (brow >= ncols) brow = ncols - 1;                 // N-tail clamp
      const unsigned short* src = B + (size_t)brow * ldb + kt * 64 + ((sw & 127) >> 1);
      GLOAD_LDS16(src, smem + 32768 + bu * 16384 + h * 8192 + g * 4096 + wave * 512);
    }
  };

  // prologue: tile0 complete + A0,B0 of tile1; drain tile0 (newest 4 stay)
  stA(0, 0, 0); stA(0, 1, 0); stB(0, 0, 0); stB(0, 1, 0);
  stA(1, 0, 1); stB(1, 0, 1);
  SCHEDB; VMCNT4; SCHEDB; BAR; SCHEDB;

#pragma unroll 1
  for (int tt = 0; tt < NT; tt += 2) {
    {
      int t1 = tt + 1;                                   // < NT always (NT even)
      int t2 = (tt + 2 < NT) ? tt + 2 : NT - 1;
      KSTEP(0, 1, t1, t2);
    }
    {
      int t1 = (tt + 2 < NT) ? tt + 2 : NT - 1;
      int t2 = (tt + 3 < NT) ? tt + 3 : NT - 1;
      KSTEP(1, 0, t1, t2);
    }
  }

#pragma unroll
  for (int mh = 0; mh < 2; ++mh)
#pragma unroll
    for (int i = 0; i < 4; ++i) {
      int grow = m0 + mh * 128 + wm * 64 + i * 16 + lquad * 4;
#pragma unroll
      for (int nh = 0; nh < 2; ++nh)
#pragma unroll
        for (int j = 0; j < 2; ++j) {
          int gcol = n0 + nh * 128 + wn * 32 + j * 16 + lrow;
          if (gcol < ncols) {
#pragma unroll
            for (int r = 0; r < 4; ++r)
              C[(size_t)(grow + r) * ldc + gcol] = acc[mh * 4 + i][nh * 2 + j][r];
          }
        }
    }
}

// ---------------- split-K reduce: out = p0+p1+p2+p3 (fp32, float4) --------
__global__ __launch_bounds__(256) void reduce_k4_kernel(
    const float* __restrict__ p, float* __restrict__ out, int n)
{
  const int S = 4194304;
  int i = (blockIdx.x * 256 + threadIdx.x) * 4;
  if (i + 4 <= n) {
    float4 a = *(const float4*)(p + i);
    float4 b = *(const float4*)(p + S + i);
    float4 c = *(const float4*)(p + 2 * S + i);
    float4 d = *(const float4*)(p + 3 * S + i);
    float4 o;
    o.x = a.x + b.x + c.x + d.x;
    o.y = a.y + b.y + c.y + d.y;
    o.z = a.z + b.z + c.z + d.z;
    o.w = a.w + b.w + c.w + d.w;
    *(float4*)(out + i) = o;
  }
}

// ---------------- tail split-K reduce: zx[row*8352+8192+col] = sum4 -------
// partials compact [4][2048][160]
__global__ __launch_bounds__(256) void reduce_tail_kernel(
    const float* __restrict__ p, float* __restrict__ zxt)
{
  const int S = 2048 * 160;
  int i = (blockIdx.x * 256 + threadIdx.x) * 4;   // 160%4==0 -> no row straddle
  if (i + 4 <= S) {
    float4 a = *(const float4*)(p + i);
    float4 b = *(const float4*)(p + S + i);
    float4 c = *(const float4*)(p + 2 * S + i);
    float4 d = *(const float4*)(p + 3 * S + i);
    float4 o;
    o.x = a.x + b.x + c.x + d.x;
    o.y = a.y + b.y + c.y + d.y;
    o.z = a.z + b.z + c.z + d.z;
    o.w = a.w + b.w + c.w + d.w;
    int row = i / 160, col = i % 160;
    *(float4*)(zxt + (size_t)row * DPROJ + col) = o;
  }
}

// ---------------- bf16 NT GEMM 64x128 tail (split-K, lda, Ncols) ----------
// B pre-offset to first tail column. C = compact partial [2048][ldcp].
__global__ __launch_bounds__(256) void gemm_nt_64tail(
    const unsigned short* __restrict__ A, const unsigned short* __restrict__ B,
    float* __restrict__ C, int Ncols, int ldcp, int lda, int Kslice)
{
  __shared__ unsigned short As[64 * 32];
  __shared__ unsigned short Bs[128 * 32];
  const int m0 = blockIdx.x * 64;
  const int n0 = blockIdx.y * 128;
  A += (size_t)blockIdx.z * Kslice;
  B += (size_t)blockIdx.z * Kslice;
  C += (size_t)blockIdx.z * 2048 * (size_t)ldcp;
  const int tid = threadIdx.x;
  const int wave = tid >> 6, lane = tid & 63;
  const int wm = (wave & 1) * 32, wn = (wave >> 1) * 64;
  const int lrow = lane & 15, lquad = lane >> 4;

  v4f acc[2][4] = {};

  for (int k0 = 0; k0 < Kslice; k0 += 32) {
    __syncthreads();
    {
      int e = wave * 64 + lane;
      int row = e >> 2;
      int kq = (e & 3) * 8;
      const unsigned short* ap = A + (size_t)(m0 + row) * lda + k0 + kq;
      GLOAD_LDS16(ap, As + wave * 512);
    }
#pragma unroll
    for (int r = 0; r < 2; ++r) {
      int e = wave * 128 + r * 64 + lane;
      int row = e >> 2;
      int kq = (e & 3) * 8;
      int br = n0 + row; if (br >= Ncols) br = Ncols - 1;
      const unsigned short* bp = B + (size_t)br * lda + k0 + kq;
      GLOAD_LDS16(bp, Bs + wave * 1024 + r * 512);
    }
    __syncthreads();
    v8s af[2], bfr[4];
#pragma unroll
    for (int i = 0; i < 2; ++i)
      af[i] = *(const v8s*)&As[(wm + i * 16 + lrow) * 32 + lquad * 8];
#pragma unroll
    for (int j = 0; j < 4; ++j)
      bfr[j] = *(const v8s*)&Bs[(wn + j * 16 + lrow) * 32 + lquad * 8];
#pragma unroll
    for (int i = 0; i < 2; ++i)
#pragma unroll
      for (int j = 0; j < 4; ++j)
        acc[i][j] = __builtin_amdgcn_mfma_f32_16x16x32_bf16(af[i], bfr[j], acc[i][j], 0, 0, 0);
  }

#pragma unroll
  for (int i = 0; i < 2; ++i) {
    int grow = m0 + wm + i * 16 + lquad * 4;
#pragma unroll
    for (int j = 0; j < 4; ++j) {
      int gcol = n0 + wn + j * 16 + lrow;
      if (gcol < Ncols) {
#pragma unroll
        for (int r = 0; r < 4; ++r)
          C[(size_t)(grow + r) * ldcp + gcol] = acc[i][j][r];
      }
    }
  }
}

// ---------------- causal depthwise conv1d(4) + SiLU, LDS-tiled ------------
__global__ __launch_bounds__(256) void conv_silu_kernel(
    const float* __restrict__ zx, const float* __restrict__ cw,
    const float* __restrict__ cb, float* __restrict__ out)
{
  const int l0 = blockIdx.x * 32, c0 = blockIdx.y * 128;
  const int tid = threadIdx.x;
  __shared__ float zs[35][128];
  __shared__ float cwl[4][128];
  __shared__ float cbl[128];
  for (int e = tid; e < 35 * 128; e += 256) {
    int k = e >> 7, cc = e & 127;
    int l = l0 + k - 3;
    zs[k][cc] = (l >= 0) ? zx[(size_t)l * DPROJ + DIN + c0 + cc] : 0.f;
  }
  for (int e = tid; e < 512; e += 256)
    cwl[e & 3][e >> 2] = cw[c0 * 4 + e];
  if (tid < 128) cbl[tid] = cb[c0 + tid];
  __syncthreads();
#pragma unroll
  for (int i = 0; i < 16; ++i) {
    int idx = i * 256 + tid;
    int ll = idx >> 7, cc = idx & 127;
    float acc = cbl[cc];
#pragma unroll
    for (int j = 0; j < 4; ++j)
      acc += zs[ll + j][cc] * cwl[j][cc];
    out[(size_t)(l0 + ll) * CONVD + c0 + cc] = acc / (1.f + __expf(-acc));
  }
}

// ---------------- dt = softplus(raw + bias) ----------------
__global__ void dt_kernel(const float* __restrict__ zx,
                          const float* __restrict__ dtb,
                          float* __restrict__ dt)
{
  int e = blockIdx.x * 256 + threadIdx.x;
  int l = e >> 5, h = e & 31;
  float v = zx[(size_t)l * DPROJ + (DPROJ - NH) + h] + dtb[h];
  dt[e] = (v > 20.f) ? v : log1pf(__expf(v));
}

// ---------------- per-(head,chunk) inclusive cumsum of A*dt ----------------
__global__ void acum_kernel(const float* __restrict__ dt,
                            const float* __restrict__ alog,
                            float* __restrict__ acum)
{
  int h = blockIdx.x & 31, c = blockIdx.x >> 5;
  int t = threadIdx.x;
  int l = c * CKLEN + t;
  float A = -__expf(alog[h]);
  __shared__ float s[256];
  s[t] = A * dt[l * NH + h];
  __syncthreads();
  for (int off = 1; off < 256; off <<= 1) {
    float add = (t >= off) ? s[t - off] : 0.f;
    __syncthreads();
    s[t] += add;
    __syncthreads();
  }
  acum[h * L_SEQ + l] = s[t];
}

// ---------------- prep: Xd (bf16 [c][h][p][t]), Btw (bf16 [c][h][n][t]),
//                  Cbf (bf16 [c][l][n], head-independent) ----------
__global__ __launch_bounds__(256) void prep_kernel(
    const float* __restrict__ xbc, const float* __restrict__ dt,
    const float* __restrict__ acum, unsigned short* __restrict__ Xd,
    unsigned short* __restrict__ Btw, unsigned short* __restrict__ Cbf)
{
  const int h = blockIdx.x & 31, c = blockIdx.x >> 5;
  const int tid = threadIdx.x;
  __shared__ float Ac[256], Dt[256], Wd[256];
  __shared__ float Xs[32][129];
  __shared__ float Bs2[32][65];
  int l = c * CKLEN + tid;
  float a = acum[h * L_SEQ + l];
  Ac[tid] = a;
  Dt[tid] = dt[l * NH + h];
  __syncthreads();
  float alast = Ac[255];
  Wd[tid] = __expf(fminf(alast - a, 0.f));
  __syncthreads();
  unsigned short* XdB = Xd + (size_t)(c * NH + h) * (HD * CKLEN);
  unsigned short* BtB = Btw + (size_t)(c * NH + h) * (NSTATE * CKLEN);
  for (int t0 = 0; t0 < CKLEN; t0 += 32) {
    for (int e = tid; e < 32 * 128; e += 256) {
      int tt = e >> 7, pp = e & 127;
      Xs[tt][pp] = xbc[(size_t)(c * CKLEN + t0 + tt) * CONVD + h * HD + pp];
    }
    for (int e = tid; e < 32 * 64; e += 256) {
      int tt = e >> 6, nn = e & 63;
      Bs2[tt][nn] = xbc[(size_t)(c * CKLEN + t0 + tt) * CONVD + DIN + nn];
    }
    __syncthreads();
    {
      int p = tid >> 1, th = (tid & 1) * 16;
      v8s r0, r1;
#pragma unroll
      for (int k = 0; k < 8; ++k) {
        r0[k] = (short)to_bf16(Xs[th + k][p] * Dt[t0 + th + k]);
        r1[k] = (short)to_bf16(Xs[th + 8 + k][p] * Dt[t0 + th + 8 + k]);
      }
      *(v8s*)&XdB[p * CKLEN + t0 + th] = r0;
      *(v8s*)&XdB[p * CKLEN + t0 + th + 8] = r1;
    }
    {
      int n = tid >> 2, tq = (tid & 3) * 8;
      v8s r;
#pragma unroll
      for (int k = 0; k < 8; ++k)
        r[k] = (short)to_bf16(Bs2[tq + k][n] * Wd[t0 + tq + k]);
      *(v8s*)&BtB[n * CKLEN + t0 + tq] = r;
    }
    __syncthreads();
  }
  if (h == 0) {
    for (int e = tid; e < CKLEN * NSTATE; e += 256) {
      int ll = e >> 6, nn = e & 63;
      Cbf[(size_t)c * (CKLEN * NSTATE) + e] =
          to_bf16(xbc[(size_t)(c * CKLEN + ll) * CONVD + DIN + NSTATE + nn]);
    }
  }
}

// ---------------- G[c][l][s] = C_l . B_s (fp32, per chunk) ----------------
__global__ __launch_bounds__(256) void g_kernel(const float* __restrict__ xbc,
                                                float* __restrict__ G)
{
  int c = blockIdx.z;
  int l0 = blockIdx.y * 64, s0 = blockIdx.x * 64;
  __shared__ float Cs[64][65];
  __shared__ float Bs[64][65];
  int tid = threadIdx.x;
  for (int e = tid; e < 64 * 64; e += 256) {
    int r = e >> 6, k = e & 63;
    Cs[r][k] = xbc[(size_t)(c * CKLEN + l0 + r) * CONVD + DIN + NSTATE + k];
    Bs[r][k] = xbc[(size_t)(c * CKLEN + s0 + r) * CONVD + DIN + k];
  }
  __syncthreads();
  int tx = tid & 15, ty = tid >> 4;
  float acc[4][4] = {};
  for (int k = 0; k < 64; ++k) {
    float a[4], b[4];
#pragma unroll
    for (int i = 0; i < 4; ++i) a[i] = Cs[ty * 4 + i][k];
#pragma unroll
    for (int j = 0; j < 4; ++j) b[j] = Bs[tx * 4 + j][k];
#pragma unroll
    for (int i = 0; i < 4; ++i)
#pragma unroll
      for (int j = 0; j < 4; ++j) acc[i][j] += a[i] * b[j];
  }
  for (int i = 0; i < 4; ++i)
    for (int j = 0; j < 4; ++j)
      G[((size_t)c * CKLEN + l0 + ty * 4 + i) * CKLEN + s0 + tx * 4 + j] = acc[i][j];
}

// ---------------- Gexp v2: G tile in LDS once, loop all 32 heads ----------
__global__ __launch_bounds__(256) void gexp_kernel_v2(
    const float* __restrict__ G, const float* __restrict__ acum,
    unsigned short* __restrict__ Gexp)
{
  const int b = blockIdx.x;
  const int si = b & 7, li = (b >> 3) & 3, c = b >> 5;
  const int l0 = li * 64, s0 = si * 32;
  const int tid = threadIdx.x;
  const int r = tid >> 2, sc = (tid & 3) * 8;

  if (s0 >= l0 + 64) {
    v8s z = {};
    for (int h = 0; h < NH; ++h)
      *(v8s*)&Gexp[(size_t)(c * NH + h) * 65536 + (size_t)(l0 + r) * 256 + s0 + sc] = z;
    return;
  }

  __shared__ float Gs[64 * 32];
  __shared__ float Acl[32][64];
  __shared__ float Acs[32][32];
  for (int e = tid; e < 2048; e += 256) {
    int rr = e >> 5, cc = e & 31;
    Gs[e] = G[(size_t)c * 65536 + (size_t)(l0 + rr) * 256 + s0 + cc];
  }
  for (int e = tid; e < 2048; e += 256) {
    int hh = e >> 6, rr = e & 63;
    Acl[hh][rr] = acum[hh * L_SEQ + c * CKLEN + l0 + rr];
  }
  for (int e = tid; e < 1024; e += 256) {
    int hh = e >> 5, ss = e & 31;
    Acs[hh][ss] = acum[hh * L_SEQ + c * CKLEN + s0 + ss];
  }
  __syncthreads();

  float g8[8];
#pragma unroll
  for (int k = 0; k < 8; ++k) g8[k] = Gs[r * 32 + sc + k];

  for (int h = 0; h < NH; ++h) {
    float al = Acl[h][r];
    v8s o;
#pragma unroll
    for (int k = 0; k < 8; ++k) {
      int s = s0 + sc + k;
      float m = 0.f;
      if (s <= l0 + r) m = g8[k] * __expf(fminf(al - Acs[h][sc + k], 0.f));
      o[k] = (short)to_bf16(m);
    }
    *(v8s*)&Gexp[(size_t)(c * NH + h) * 65536 + (size_t)(l0 + r) * 256 + s0 + sc] = o;
  }
}

// ---------------- chunk states: st[p][n] = Xd[p][:] . Btw[n][:] -----------
__global__ __launch_bounds__(256) void states_kernel_v2(
    const unsigned short* __restrict__ Xd, const unsigned short* __restrict__ Btw,
    float* __restrict__ st)
{
  const int h = blockIdx.x & 31, c = blockIdx.x >> 5;
  const int tid = threadIdx.x;
  const int wave = tid >> 6, lane = tid & 63;
  const int wm = (wave & 1) * 64, wn = (wave >> 1) * 32;
  const int lrow = lane & 15, lquad = lane >> 4;

  __shared__ unsigned short As[128 * 32];
  __shared__ unsigned short Bs[64 * 32];
  const unsigned short* Ab = Xd + (size_t)(c * NH + h) * (HD * CKLEN);
  const unsigned short* Bb = Btw + (size_t)(c * NH + h) * (NSTATE * CKLEN);

  v4f acc[4][2] = {};

  for (int k0 = 0; k0 < CKLEN; k0 += 32) {
    __syncthreads();
#pragma unroll
    for (int r = 0; r < 2; ++r) {
      int e = wave * 128 + r * 64 + lane;
      int row = e >> 2, kq = (e & 3) * 8;
      GLOAD_LDS16(Ab + (size_t)row * CKLEN + k0 + kq, As + wave * 1024 + r * 512);
    }
    {
      int e = wave * 64 + lane;
      int row = e >> 2, kq = (e & 3) * 8;
      GLOAD_LDS16(Bb + (size_t)row * CKLEN + k0 + kq, Bs + wave * 512);
    }
    __syncthreads();
    v8s af[4], bfr[2];
#pragma unroll
    for (int i = 0; i < 4; ++i)
      af[i] = *(const v8s*)&As[(wm + i * 16 + lrow) * 32 + lquad * 8];
#pragma unroll
    for (int j = 0; j < 2; ++j)
      bfr[j] = *(const v8s*)&Bs[(wn + j * 16 + lrow) * 32 + lquad * 8];
#pragma unroll
    for (int i = 0; i < 4; ++i)
#pragma unroll
      for (int j = 0; j < 2; ++j)
        acc[i][j] = __builtin_amdgcn_mfma_f32_16x16x32_bf16(af[i], bfr[j], acc[i][j], 0, 0, 0);
  }

  float* outp = st + (size_t)(c * NH + h) * (HD * NSTATE);
#pragma unroll
  for (int i = 0; i < 4; ++i) {
    int p0 = wm + i * 16 + lquad * 4;
#pragma unroll
    for (int j = 0; j < 2; ++j) {
      int n = wn + j * 16 + lrow;
#pragma unroll
      for (int r = 0; r < 4; ++r)
        outp[(size_t)(p0 + r) * NSTATE + n] = acc[i][j][r];
    }
  }
}

// ---------------- inter-chunk scan -> bf16 sp ----------------
__global__ void scan_kernel(const float* __restrict__ acum,
                            const float* __restrict__ st,
                            unsigned short* __restrict__ spbf)
{
  int e = blockIdx.x * 256 + threadIdx.x;
  int h = e >> 13;
  float running = 0.f;
#pragma unroll
  for (int c = 0; c < NCHUNK; ++c) {
    spbf[(size_t)c * 262144 + e] = to_bf16(running);
    float dec = __expf(fminf(acum[h * L_SEQ + c * CKLEN + 255], 0.f));
    running = running * dec + st[(size_t)c * 262144 + e];
  }
}

// ---------------- Y: acc = Cbf @ sp^T; acc *= exp(Ac[l]); acc += Gexp @ Xd^T;
//                  Y = acc + D*xs ----------------
__global__ __launch_bounds__(256) void y_kernel_v2(
    const unsigned short* __restrict__ Gexp, const unsigned short* __restrict__ Xd,
    const unsigned short* __restrict__ Cbf, const unsigned short* __restrict__ spbf,
    const float* __restrict__ xbc, const float* __restrict__ acum,
    const float* __restrict__ Dp, float* __restrict__ Y)
{
  const int b = blockIdx.x, h = blockIdx.y, c = blockIdx.z;
  const int tid = threadIdx.x;
  const int wave = tid >> 6, lane = tid & 63;
  const int wm = wave * 32;
  const int lrow = lane & 15, lquad = lane >> 4;

  __shared__ unsigned short As[128 * 32];
  __shared__ unsigned short Bs[128 * 32];

  v4f acc[2][8] = {};

  const unsigned short* Ca = Cbf + (size_t)c * (CKLEN * NSTATE) + (size_t)b * 128 * NSTATE;
  const unsigned short* Sb = spbf + (size_t)(c * NH + h) * (HD * NSTATE);
  for (int n0 = 0; n0 < NSTATE; n0 += 32) {
    __syncthreads();
#pragma unroll
    for (int r = 0; r < 2; ++r) {
      int e = wave * 128 + r * 64 + lane;
      int row = e >> 2, kq = (e & 3) * 8;
      GLOAD_LDS16(Ca + (size_t)row * NSTATE + n0 + kq, As + wave * 1024 + r * 512);
      GLOAD_LDS16(Sb + (size_t)row * NSTATE + n0 + kq, Bs + wave * 1024 + r * 512);
    }
    __syncthreads();
    v8s af[2], bfr[8];
#pragma unroll
    for (int i = 0; i < 2; ++i)
      af[i] = *(const v8s*)&As[(wm + i * 16 + lrow) * 32 + lquad * 8];
#pragma unroll
    for (int j = 0; j < 8; ++j)
      bfr[j] = *(const v8s*)&Bs[(j * 16 + lrow) * 32 + lquad * 8];
#pragma unroll
    for (int i = 0; i < 2; ++i)
#pragma unroll
      for (int j = 0; j < 8; ++j)
        acc[i][j] = __builtin_amdgcn_mfma_f32_16x16x32_bf16(af[i], bfr[j], acc[i][j], 0, 0, 0);
  }

#pragma unroll
  for (int i = 0; i < 2; ++i) {
#pragma unroll
    for (int r = 0; r < 4; ++r) {
      int Lg = c * CKLEN + b * 128 + wm + i * 16 + lquad * 4 + r;
      float eA = __expf(fminf(acum[h * L_SEQ + Lg], 0.f));
#pragma unroll
      for (int j = 0; j < 8; ++j) acc[i][j][r] *= eA;
    }
  }

  const unsigned short* Ga = Gexp + (size_t)(c * NH + h) * (CKLEN * CKLEN)
                           + (size_t)b * 128 * CKLEN;
  const unsigned short* Xb = Xd + (size_t)(c * NH + h) * (HD * CKLEN);

  const int smax = (b + 1) * 128;
  for (int s0 = 0; s0 < smax; s0 += 32) {
    __syncthreads();
#pragma unroll
    for (int r = 0; r < 2; ++r) {
      int e = wave * 128 + r * 64 + lane;
      int row = e >> 2, kq = (e & 3) * 8;
      GLOAD_LDS16(Ga + (size_t)row * CKLEN + s0 + kq, As + wave * 1024 + r * 512);
      GLOAD_LDS16(Xb + (size_t)row * CKLEN + s0 + kq, Bs + wave * 1024 + r * 512);
    }
    __syncthreads();
    if (s0 <= b * 128 + wm + 31) {
      v8s af[2], bfr[8];
#pragma unroll
      for (int i = 0; i < 2; ++i)
        af[i] = *(const v8s*)&As[(wm + i * 16 + lrow) * 32 + lquad * 8];
#pragma unroll
      for (int j = 0; j < 8; ++j)
        bfr[j] = *(const v8s*)&Bs[(j * 16 + lrow) * 32 + lquad * 8];
#pragma unroll
      for (int i = 0; i < 2; ++i)
#pragma unroll
        for (int j = 0; j < 8; ++j)
          acc[i][j] = __builtin_amdgcn_mfma_f32_16x16x32_bf16(af[i], bfr[j], acc[i][j], 0, 0, 0);
    }
  }

  const float Dh = Dp[h];
#pragma unroll
  for (int i = 0; i < 2; ++i) {
#pragma unroll
    for (int j = 0; j < 8; ++j) {
      int p = j * 16 + lrow;
#pragma unroll
      for (int r = 0; r < 4; ++r) {
        int Lg = c * CKLEN + b * 128 + wm + i * 16 + lquad * 4 + r;
        float xs = xbc[(size_t)Lg * CONVD + h * HD + p];
        Y[(size_t)Lg * DIN + h * HD + p] = acc[i][j][r] + Dh * xs;
      }
    }
  }
}

// ---------------- gated RMSNorm -> bf16 ----------------
__global__ __launch_bounds__(256) void norm_gate_kernel(const float* __restrict__ Y,
                                                        const float* __restrict__ zx,
                                                        const float* __restrict__ nw,
                                                        unsigned short* __restrict__ gbf)
{
  int l = blockIdx.x;
  int t = threadIdx.x;
  float g[16];
  float ss = 0.f;
#pragma unroll
  for (int i = 0; i < 16; ++i) {
    int idx = i * 256 + t;
    float z = zx[(size_t)l * DPROJ + idx];
    float y = Y[(size_t)l * DIN + idx];
    float gv = y * (z / (1.f + __expf(-z)));
    g[i] = gv;
    ss += gv * gv;
  }
#pragma unroll
  for (int off = 32; off > 0; off >>= 1) ss += __shfl_down(ss, off);
  __shared__ float red[4];
  if ((t & 63) == 0) red[t >> 6] = ss;
  __syncthreads();
  float total = red[0] + red[1] + red[2] + red[3];
  float scale = rsqrtf(total / (float)DIN + 1e-5f);
#pragma unroll
  for (int i = 0; i < 16; ++i) {
    int idx = i * 256 + t;
    gbf[(size_t)l * DIN + idx] = to_bf16(g[i] * scale * nw[idx]);
  }
}

// ---------------- launch ----------------
extern "C" void kernel_launch(void* const* d_in, const int* in_sizes, int n_in,
                              void* d_out, int out_size, void* d_ws, size_t ws_size,
                              hipStream_t stream) {
  const float* x    = (const float*)d_in[0];
  const float* w1   = (const float*)d_in[1];
  const float* cw   = (const float*)d_in[2];
  const float* cb   = (const float*)d_in[3];
  const float* dtb  = (const float*)d_in[4];
  const float* alog = (const float*)d_in[5];
  const float* Dp   = (const float*)d_in[6];
  const float* nw   = (const float*)d_in[7];
  const float* w2   = (const float*)d_in[8];
  float* out = (float*)d_out;
  float* ws  = (float*)d_ws;

  // scratch layout (float units). Gexp/Btw overlay xbf/w1bf (dead after gemm1).
  // zx region reused for gemm2 split-K partials (zx dead after norm_gate).
  // st region doubles as gemm1-tail split-K partials (st written later).
  unsigned short* xbf  = (unsigned short*)(ws + 0);          // 2048*2048 bf16
  unsigned short* w1bf = (unsigned short*)(ws + 2097152);    // 8352*2048 bf16
  unsigned short* Gexp = (unsigned short*)(ws + 0);          // 8*32*256*256 bf16 (post-gemm1)
  unsigned short* Btw  = (unsigned short*)(ws + 8388608);    // 8*32*64*256 bf16 (post-gemm1)
  unsigned short* w2bf = (unsigned short*)(ws + 10649600);   // 2048*4096 bf16
  float* zx   = ws + 14843904;   // 2048*8352
  float* part = ws + 14843904;   // 4*2048*2048 fp32 partials (post-norm_gate)
  float* xbc  = ws + 31948800;   // 2048*4224
  float* dt   = ws + 40599552;   // 2048*32
  float* acum = ws + 40665088;   // 32*2048
  float* G    = ws + 40730624;   // 8*256*256 fp32
  float* st   = ws + 41254912;   // 8*32*128*64 fp32 (also: 4*2048*160 tail partials, pre-states)
  float* Y    = ws + 43352064;   // 2048*4096
  unsigned short* gbf  = (unsigned short*)(ws + 51740672);   // 2048*4096 bf16
  unsigned short* Xd   = (unsigned short*)(ws + 53837824);   // 8*32*128*256 bf16
  unsigned short* Cbf  = (unsigned short*)(ws + 58032128);   // 8*256*64 bf16
  unsigned short* spbf = (unsigned short*)(ws + 58097664);   // 8*32*128*64 bf16

  cvt_bf16_kernel<<<4194304 / 2048, 256, 0, stream>>>(x, xbf, 4194304);
  cvt_bf16_kernel<<<17104896 / 2048, 256, 0, stream>>>(w1, w1bf, 17104896);
  cvt_bf16_kernel<<<8388608 / 2048, 256, 0, stream>>>(w2, w2bf, 8388608);

  // zxbcdt = x @ in_proj_w^T   (M=2048, N=8352, K=2048)
  // main: 256x256 8-phase + XCD swizzle on cols 0..8191 (256 blocks, 1 round)
  gemm_nt_256<<<dim3(8, 32, 1), 512, 0, stream>>>(
      xbf, w1bf, zx, 2048, 2048, 8352, 8352, 2048);
  // tail: cols 8192..8351 (160 cols), split-K x4 (256 blocks) -> st scratch
  gemm_nt_64tail<<<dim3(32, 2, 4), 256, 0, stream>>>(
      xbf, w1bf + (size_t)8192 * 2048, st, 160, 160, 2048, 512);
  reduce_tail_kernel<<<320, 256, 0, stream>>>(st, zx + 8192);

  conv_silu_kernel<<<dim3(64, 33), 256, 0, stream>>>(zx, cw, cb, xbc);
  dt_kernel<<<(L_SEQ * NH) / 256, 256, 0, stream>>>(zx, dtb, dt);
  acum_kernel<<<NCHUNK * NH, 256, 0, stream>>>(dt, alog, acum);

  prep_kernel<<<NCHUNK * NH, 256, 0, stream>>>(xbc, dt, acum, Xd, Btw, Cbf);
  g_kernel<<<dim3(4, 4, NCHUNK), 256, 0, stream>>>(xbc, G);
  gexp_kernel_v2<<<256, 256, 0, stream>>>(G, acum, Gexp);

  states_kernel_v2<<<NCHUNK * NH, 256, 0, stream>>>(Xd, Btw, st);
  scan_kernel<<<262144 / 256, 256, 0, stream>>>(acum, st, spbf);
  y_kernel_v2<<<dim3(2, NH, NCHUNK), 256, 0, stream>>>(Gexp, Xd, Cbf, spbf, xbc, acum, Dp, Y);

  norm_gate_kernel<<<L_SEQ, 256, 0, stream>>>(Y, zx, nw, gbf);

  // out = g @ out_proj_w^T (M=2048, N=2048, K=4096): split-K x4 through the
  // 256x256 8-phase kernel (grid 8x8x4 = 256 blocks, K=1024/split), fp32
  // partials in the dead zx region, then a float4 reduce.
  gemm_nt_256<<<dim3(8, 8, 4), 512, 0, stream>>>(
      gbf, w2bf, part, 4096, 4096, 2048, 2048, 1024);
  reduce_k4_kernel<<<4194304 / 1024, 256, 0, stream>>>(part, out, 4194304);
}

// Round 14
// 406.050 us; speedup vs baseline: 1.1194x; 1.0498x over previous
//
#include <hip/hip_runtime.h>

typedef short v8s __attribute__((ext_vector_type(8)));
typedef float v4f __attribute__((ext_vector_type(4)));

// ---- problem constants ----
#define L_SEQ  2048
#define DPROJ  8352
#define CONVD  4224
#define DIN    4096
#define NH     32
#define HD     128
#define NSTATE 64
#define NCHUNK 8
#define CKLEN  256

#define GLOAD_LDS16(gp, lp) \
  __builtin_amdgcn_global_load_lds((const __attribute__((address_space(1))) void*)(gp), \
                                   (__attribute__((address_space(3))) void*)(lp), 16, 0, 0)

__device__ __forceinline__ unsigned short to_bf16(float f) {
  unsigned u = __float_as_uint(f);
  return (unsigned short)((u + 0x7fffu + ((u >> 16) & 1u)) >> 16);
}

// ---------------- fp32 -> bf16 cast, 8 elts/thread ----------------
__global__ void cvt_bf16_kernel(const float* __restrict__ in,
                                unsigned short* __restrict__ out, int n) {
  int i = (blockIdx.x * 256 + threadIdx.x) * 8;
  if (i + 8 <= n) {
    float4 a = *(const float4*)(in + i);
    float4 b = *(const float4*)(in + i + 4);
    v8s r;
    r[0] = (short)to_bf16(a.x); r[1] = (short)to_bf16(a.y);
    r[2] = (short)to_bf16(a.z); r[3] = (short)to_bf16(a.w);
    r[4] = (short)to_bf16(b.x); r[5] = (short)to_bf16(b.y);
    r[6] = (short)to_bf16(b.z); r[7] = (short)to_bf16(b.w);
    *(v8s*)(out + i) = r;
  }
}

// ---------------- 256x256 8-phase bf16 NT GEMM (T1+T2+T3+T4+T5) -------------
// Verified R6/R11: SQ_LDS_BANK_CONFLICT=0; T1 swizzle FETCH 136->50MB.

#define BAR    __builtin_amdgcn_s_barrier()
#define SCHEDB __builtin_amdgcn_sched_barrier(0)
#define LGKM0  asm volatile("s_waitcnt lgkmcnt(0)" ::: "memory")
#define VMCNT4 asm volatile("s_waitcnt vmcnt(4)" ::: "memory")

#define RDA(bu, mh) do { \
  _Pragma("unroll") \
  for (int i = 0; i < 4; ++i) \
    _Pragma("unroll") \
    for (int s = 0; s < 2; ++s) { \
      int row_ = (mh) * 128 + wm * 64 + i * 16 + lrow; \
      int off_ = row_ * 128 + s * 64 + lquad * 16; \
      off_ ^= ((off_ >> 7) & 7) << 4; \
      a8[i][s] = *(const v8s*)((const char*)smem + (bu) * 32768 + off_); \
    } \
} while (0)

#define RDB(bu, nh) do { \
  _Pragma("unroll") \
  for (int j = 0; j < 2; ++j) \
    _Pragma("unroll") \
    for (int s = 0; s < 2; ++s) { \
      int row_ = (nh) * 128 + wn * 32 + j * 16 + lrow; \
      int off_ = row_ * 128 + s * 64 + lquad * 16; \
      off_ ^= ((off_ >> 7) & 7) << 4; \
      b8[nh][j][s] = *(const v8s*)((const char*)smem + 65536 + (bu) * 32768 + off_); \
    } \
} while (0)

#define MM(mh, nh) do { \
  __builtin_amdgcn_s_setprio(1); \
  _Pragma("unroll") \
  for (int i = 0; i < 4; ++i) \
    _Pragma("unroll") \
    for (int j = 0; j < 2; ++j) \
      _Pragma("unroll") \
      for (int s = 0; s < 2; ++s) \
        acc[(mh)*4+i][(nh)*2+j] = __builtin_amdgcn_mfma_f32_16x16x32_bf16( \
            a8[i][s], b8[(nh)][j][s], acc[(mh)*4+i][(nh)*2+j], 0, 0, 0); \
  __builtin_amdgcn_s_setprio(0); \
} while (0)

#define KSTEP(BU, BN_, T1, T2) do { \
  RDA(BU, 0); RDB(BU, 0); \
  stA(BN_, 1, T1); \
  BAR; LGKM0; SCHEDB; \
  MM(0, 0); \
  BAR; \
  RDB(BU, 1); \
  stB(BN_, 1, T1); \
  BAR; LGKM0; SCHEDB; \
  MM(0, 1); \
  BAR; \
  RDA(BU, 1); \
  stA(BU, 0, T2); \
  BAR; LGKM0; SCHEDB; \
  MM(1, 0); \
  BAR; \
  stB(BU, 0, T2); \
  BAR; \
  MM(1, 1); \
  SCHEDB; VMCNT4; SCHEDB; \
  BAR; SCHEDB; \
} while (0)

__global__ __launch_bounds__(512, 2) void gemm_nt_256(
    const unsigned short* __restrict__ A, const unsigned short* __restrict__ B,
    float* __restrict__ C, int lda, int ldb, int ldc, int ncols, int K)
{
  __shared__ unsigned short smem[65536];   // 128 KiB: [A0|A1|B0|B1] 32KB each
  // T1 XCD swizzle (bijective, nwg%8==0): XCD k <- contiguous by-chunk.
  const int nwgx = gridDim.x;
  const int nwg  = nwgx * gridDim.y;
  const int lin  = blockIdx.x + nwgx * blockIdx.y;
  const int q    = nwg >> 3;
  const int swz  = (lin & 7) * q + (lin >> 3);
  const int m0 = (swz % nwgx) * 256;
  const int n0 = (swz / nwgx) * 256;
  // split-K offsets (bz=0 -> no-op)
  A += (size_t)blockIdx.z * K;
  B += (size_t)blockIdx.z * K;
  C += (size_t)blockIdx.z * 2048 * (size_t)ldc;
  const int tid = threadIdx.x;
  const int wave = tid >> 6, lane = tid & 63;
  const int wm = wave >> 2, wn = wave & 3;
  const int lrow = lane & 15, lquad = lane >> 4;
  const int NT = K >> 6;

  v4f acc[8][4] = {};
  v8s a8[4][2];
  v8s b8[2][2][2];

  auto stA = [&](int bu, int h, int kt) {
#pragma unroll
    for (int g = 0; g < 2; ++g) {
      int lin2 = h * 16384 + g * 8192 + tid * 16;          // byte off in region
      int sw = lin2 ^ (((lin2 >> 7) & 7) << 4);
      int row = sw >> 7;                                   // region row 0..255
      const unsigned short* src = A + (size_t)(m0 + row) * lda + kt * 64 + ((sw & 127) >> 1);
      GLOAD_LDS16(src, smem + bu * 16384 + h * 8192 + g * 4096 + wave * 512);
    }
  };
  auto stB = [&](int bu, int h, int kt) {
#pragma unroll
    for (int g = 0; g < 2; ++g) {
      int lin2 = h * 16384 + g * 8192 + tid * 16;
      int sw = lin2 ^ (((lin2 >> 7) & 7) << 4);
      int brow = n0 + (sw >> 7);
      if (brow >= ncols) brow = ncols - 1;                 // N-tail clamp
      const unsigned short* src = B + (size_t)brow * ldb + kt * 64 + ((sw & 127) >> 1);
      GLOAD_LDS16(src, smem + 32768 + bu * 16384 + h * 8192 + g * 4096 + wave * 512);
    }
  };

  // prologue: tile0 complete + A0,B0 of tile1; drain tile0 (newest 4 stay)
  stA(0, 0, 0); stA(0, 1, 0); stB(0, 0, 0); stB(0, 1, 0);
  stA(1, 0, 1); stB(1, 0, 1);
  SCHEDB; VMCNT4; SCHEDB; BAR; SCHEDB;

#pragma unroll 1
  for (int tt = 0; tt < NT; tt += 2) {
    {
      int t1 = tt + 1;                                   // < NT always (NT even)
      int t2 = (tt + 2 < NT) ? tt + 2 : NT - 1;
      KSTEP(0, 1, t1, t2);
    }
    {
      int t1 = (tt + 2 < NT) ? tt + 2 : NT - 1;
      int t2 = (tt + 3 < NT) ? tt + 3 : NT - 1;
      KSTEP(1, 0, t1, t2);
    }
  }

#pragma unroll
  for (int mh = 0; mh < 2; ++mh)
#pragma unroll
    for (int i = 0; i < 4; ++i) {
      int grow = m0 + mh * 128 + wm * 64 + i * 16 + lquad * 4;
#pragma unroll
      for (int nh = 0; nh < 2; ++nh)
#pragma unroll
        for (int j = 0; j < 2; ++j) {
          int gcol = n0 + nh * 128 + wn * 32 + j * 16 + lrow;
          if (gcol < ncols) {
#pragma unroll
            for (int r = 0; r < 4; ++r)
              C[(size_t)(grow + r) * ldc + gcol] = acc[mh * 4 + i][nh * 2 + j][r];
          }
        }
    }
}

// ---------------- split-K reduce: out = p0+p1+p2+p3 (fp32, float4) --------
__global__ __launch_bounds__(256) void reduce_k4_kernel(
    const float* __restrict__ p, float* __restrict__ out, int n)
{
  const int S = 4194304;
  int i = (blockIdx.x * 256 + threadIdx.x) * 4;
  if (i + 4 <= n) {
    float4 a = *(const float4*)(p + i);
    float4 b = *(const float4*)(p + S + i);
    float4 c = *(const float4*)(p + 2 * S + i);
    float4 d = *(const float4*)(p + 3 * S + i);
    float4 o;
    o.x = a.x + b.x + c.x + d.x;
    o.y = a.y + b.y + c.y + d.y;
    o.z = a.z + b.z + c.z + d.z;
    o.w = a.w + b.w + c.w + d.w;
    *(float4*)(out + i) = o;
  }
}

// ---------------- tail split-K reduce: zx[row*8352+8192+col] = sum4 -------
// partials compact [4][2048][160]
__global__ __launch_bounds__(256) void reduce_tail_kernel(
    const float* __restrict__ p, float* __restrict__ zxt)
{
  const int S = 2048 * 160;
  int i = (blockIdx.x * 256 + threadIdx.x) * 4;   // 160%4==0 -> no row straddle
  if (i + 4 <= S) {
    float4 a = *(const float4*)(p + i);
    float4 b = *(const float4*)(p + S + i);
    float4 c = *(const float4*)(p + 2 * S + i);
    float4 d = *(const float4*)(p + 3 * S + i);
    float4 o;
    o.x = a.x + b.x + c.x + d.x;
    o.y = a.y + b.y + c.y + d.y;
    o.z = a.z + b.z + c.z + d.z;
    o.w = a.w + b.w + c.w + d.w;
    int row = i / 160, col = i % 160;
    *(float4*)(zxt + (size_t)row * DPROJ + col) = o;
  }
}

// ---------------- bf16 NT GEMM 64x128 tail (split-K, lda, Ncols) ----------
// B pre-offset to first tail column. C = compact partial [2048][ldcp].
__global__ __launch_bounds__(256) void gemm_nt_64tail(
    const unsigned short* __restrict__ A, const unsigned short* __restrict__ B,
    float* __restrict__ C, int Ncols, int ldcp, int lda, int Kslice)
{
  __shared__ unsigned short As[64 * 32];
  __shared__ unsigned short Bs[128 * 32];
  const int m0 = blockIdx.x * 64;
  const int n0 = blockIdx.y * 128;
  A += (size_t)blockIdx.z * Kslice;
  B += (size_t)blockIdx.z * Kslice;
  C += (size_t)blockIdx.z * 2048 * (size_t)ldcp;
  const int tid = threadIdx.x;
  const int wave = tid >> 6, lane = tid & 63;
  const int wm = (wave & 1) * 32, wn = (wave >> 1) * 64;
  const int lrow = lane & 15, lquad = lane >> 4;

  v4f acc[2][4] = {};

  for (int k0 = 0; k0 < Kslice; k0 += 32) {
    __syncthreads();
    {
      int e = wave * 64 + lane;
      int row = e >> 2;
      int kq = (e & 3) * 8;
      const unsigned short* ap = A + (size_t)(m0 + row) * lda + k0 + kq;
      GLOAD_LDS16(ap, As + wave * 512);
    }
#pragma unroll
    for (int r = 0; r < 2; ++r) {
      int e = wave * 128 + r * 64 + lane;
      int row = e >> 2;
      int kq = (e & 3) * 8;
      int br = n0 + row; if (br >= Ncols) br = Ncols - 1;
      const unsigned short* bp = B + (size_t)br * lda + k0 + kq;
      GLOAD_LDS16(bp, Bs + wave * 1024 + r * 512);
    }
    __syncthreads();
    v8s af[2], bfr[4];
#pragma unroll
    for (int i = 0; i < 2; ++i)
      af[i] = *(const v8s*)&As[(wm + i * 16 + lrow) * 32 + lquad * 8];
#pragma unroll
    for (int j = 0; j < 4; ++j)
      bfr[j] = *(const v8s*)&Bs[(wn + j * 16 + lrow) * 32 + lquad * 8];
#pragma unroll
    for (int i = 0; i < 2; ++i)
#pragma unroll
      for (int j = 0; j < 4; ++j)
        acc[i][j] = __builtin_amdgcn_mfma_f32_16x16x32_bf16(af[i], bfr[j], acc[i][j], 0, 0, 0);
  }

#pragma unroll
  for (int i = 0; i < 2; ++i) {
    int grow = m0 + wm + i * 16 + lquad * 4;
#pragma unroll
    for (int j = 0; j < 4; ++j) {
      int gcol = n0 + wn + j * 16 + lrow;
      if (gcol < Ncols) {
#pragma unroll
        for (int r = 0; r < 4; ++r)
          C[(size_t)(grow + r) * ldcp + gcol] = acc[i][j][r];
      }
    }
  }
}

// ---------------- causal depthwise conv1d(4) + SiLU, LDS-tiled ------------
__global__ __launch_bounds__(256) void conv_silu_kernel(
    const float* __restrict__ zx, const float* __restrict__ cw,
    const float* __restrict__ cb, float* __restrict__ out)
{
  const int l0 = blockIdx.x * 32, c0 = blockIdx.y * 128;
  const int tid = threadIdx.x;
  __shared__ float zs[35][128];
  __shared__ float cwl[4][128];
  __shared__ float cbl[128];
  for (int e = tid; e < 35 * 128; e += 256) {
    int k = e >> 7, cc = e & 127;
    int l = l0 + k - 3;
    zs[k][cc] = (l >= 0) ? zx[(size_t)l * DPROJ + DIN + c0 + cc] : 0.f;
  }
  for (int e = tid; e < 512; e += 256)
    cwl[e & 3][e >> 2] = cw[c0 * 4 + e];
  if (tid < 128) cbl[tid] = cb[c0 + tid];
  __syncthreads();
#pragma unroll
  for (int i = 0; i < 16; ++i) {
    int idx = i * 256 + tid;
    int ll = idx >> 7, cc = idx & 127;
    float acc = cbl[cc];
#pragma unroll
    for (int j = 0; j < 4; ++j)
      acc += zs[ll + j][cc] * cwl[j][cc];
    out[(size_t)(l0 + ll) * CONVD + c0 + cc] = acc / (1.f + __expf(-acc));
  }
}

// ---------------- dt = softplus(raw + bias) ----------------
__global__ void dt_kernel(const float* __restrict__ zx,
                          const float* __restrict__ dtb,
                          float* __restrict__ dt)
{
  int e = blockIdx.x * 256 + threadIdx.x;
  int l = e >> 5, h = e & 31;
  float v = zx[(size_t)l * DPROJ + (DPROJ - NH) + h] + dtb[h];
  dt[e] = (v > 20.f) ? v : log1pf(__expf(v));
}

// ---------------- per-(head,chunk) inclusive cumsum of A*dt ----------------
__global__ void acum_kernel(const float* __restrict__ dt,
                            const float* __restrict__ alog,
                            float* __restrict__ acum)
{
  int h = blockIdx.x & 31, c = blockIdx.x >> 5;
  int t = threadIdx.x;
  int l = c * CKLEN + t;
  float A = -__expf(alog[h]);
  __shared__ float s[256];
  s[t] = A * dt[l * NH + h];
  __syncthreads();
  for (int off = 1; off < 256; off <<= 1) {
    float add = (t >= off) ? s[t - off] : 0.f;
    __syncthreads();
    s[t] += add;
    __syncthreads();
  }
  acum[h * L_SEQ + l] = s[t];
}

// ---------------- prep: Xd (bf16 [c][h][p][t]), Btw (bf16 [c][h][n][t]),
//                  Cbf (bf16 [c][l][n], head-independent) ----------
__global__ __launch_bounds__(256) void prep_kernel(
    const float* __restrict__ xbc, const float* __restrict__ dt,
    const float* __restrict__ acum, unsigned short* __restrict__ Xd,
    unsigned short* __restrict__ Btw, unsigned short* __restrict__ Cbf)
{
  const int h = blockIdx.x & 31, c = blockIdx.x >> 5;
  const int tid = threadIdx.x;
  __shared__ float Ac[256], Dt[256], Wd[256];
  __shared__ float Xs[32][129];
  __shared__ float Bs2[32][65];
  int l = c * CKLEN + tid;
  float a = acum[h * L_SEQ + l];
  Ac[tid] = a;
  Dt[tid] = dt[l * NH + h];
  __syncthreads();
  float alast = Ac[255];
  Wd[tid] = __expf(fminf(alast - a, 0.f));
  __syncthreads();
  unsigned short* XdB = Xd + (size_t)(c * NH + h) * (HD * CKLEN);
  unsigned short* BtB = Btw + (size_t)(c * NH + h) * (NSTATE * CKLEN);
  for (int t0 = 0; t0 < CKLEN; t0 += 32) {
    for (int e = tid; e < 32 * 128; e += 256) {
      int tt = e >> 7, pp = e & 127;
      Xs[tt][pp] = xbc[(size_t)(c * CKLEN + t0 + tt) * CONVD + h * HD + pp];
    }
    for (int e = tid; e < 32 * 64; e += 256) {
      int tt = e >> 6, nn = e & 63;
      Bs2[tt][nn] = xbc[(size_t)(c * CKLEN + t0 + tt) * CONVD + DIN + nn];
    }
    __syncthreads();
    {
      int p = tid >> 1, th = (tid & 1) * 16;
      v8s r0, r1;
#pragma unroll
      for (int k = 0; k < 8; ++k) {
        r0[k] = (short)to_bf16(Xs[th + k][p] * Dt[t0 + th + k]);
        r1[k] = (short)to_bf16(Xs[th + 8 + k][p] * Dt[t0 + th + 8 + k]);
      }
      *(v8s*)&XdB[p * CKLEN + t0 + th] = r0;
      *(v8s*)&XdB[p * CKLEN + t0 + th + 8] = r1;
    }
    {
      int n = tid >> 2, tq = (tid & 3) * 8;
      v8s r;
#pragma unroll
      for (int k = 0; k < 8; ++k)
        r[k] = (short)to_bf16(Bs2[tq + k][n] * Wd[t0 + tq + k]);
      *(v8s*)&BtB[n * CKLEN + t0 + tq] = r;
    }
    __syncthreads();
  }
  if (h == 0) {
    for (int e = tid; e < CKLEN * NSTATE; e += 256) {
      int ll = e >> 6, nn = e & 63;
      Cbf[(size_t)c * (CKLEN * NSTATE) + e] =
          to_bf16(xbc[(size_t)(c * CKLEN + ll) * CONVD + DIN + NSTATE + nn]);
    }
  }
}

// ---------------- G[c][l][s] = C_l . B_s (fp32, per chunk) ----------------
__global__ __launch_bounds__(256) void g_kernel(const float* __restrict__ xbc,
                                                float* __restrict__ G)
{
  int c = blockIdx.z;
  int l0 = blockIdx.y * 64, s0 = blockIdx.x * 64;
  __shared__ float Cs[64][65];
  __shared__ float Bs[64][65];
  int tid = threadIdx.x;
  for (int e = tid; e < 64 * 64; e += 256) {
    int r = e >> 6, k = e & 63;
    Cs[r][k] = xbc[(size_t)(c * CKLEN + l0 + r) * CONVD + DIN + NSTATE + k];
    Bs[r][k] = xbc[(size_t)(c * CKLEN + s0 + r) * CONVD + DIN + k];
  }
  __syncthreads();
  int tx = tid & 15, ty = tid >> 4;
  float acc[4][4] = {};
  for (int k = 0; k < 64; ++k) {
    float a[4], b[4];
#pragma unroll
    for (int i = 0; i < 4; ++i) a[i] = Cs[ty * 4 + i][k];
#pragma unroll
    for (int j = 0; j < 4; ++j) b[j] = Bs[tx * 4 + j][k];
#pragma unroll
    for (int i = 0; i < 4; ++i)
#pragma unroll
      for (int j = 0; j < 4; ++j) acc[i][j] += a[i] * b[j];
  }
  for (int i = 0; i < 4; ++i)
    for (int j = 0; j < 4; ++j)
      G[((size_t)c * CKLEN + l0 + ty * 4 + i) * CKLEN + s0 + tx * 4 + j] = acc[i][j];
}

// ---------------- chunk states: st[p][n] = Xd[p][:] . Btw[n][:] -----------
__global__ __launch_bounds__(256) void states_kernel_v2(
    const unsigned short* __restrict__ Xd, const unsigned short* __restrict__ Btw,
    float* __restrict__ st)
{
  const int h = blockIdx.x & 31, c = blockIdx.x >> 5;
  const int tid = threadIdx.x;
  const int wave = tid >> 6, lane = tid & 63;
  const int wm = (wave & 1) * 64, wn = (wave >> 1) * 32;
  const int lrow = lane & 15, lquad = lane >> 4;

  __shared__ unsigned short As[128 * 32];
  __shared__ unsigned short Bs[64 * 32];
  const unsigned short* Ab = Xd + (size_t)(c * NH + h) * (HD * CKLEN);
  const unsigned short* Bb = Btw + (size_t)(c * NH + h) * (NSTATE * CKLEN);

  v4f acc[4][2] = {};

  for (int k0 = 0; k0 < CKLEN; k0 += 32) {
    __syncthreads();
#pragma unroll
    for (int r = 0; r < 2; ++r) {
      int e = wave * 128 + r * 64 + lane;
      int row = e >> 2, kq = (e & 3) * 8;
      GLOAD_LDS16(Ab + (size_t)row * CKLEN + k0 + kq, As + wave * 1024 + r * 512);
    }
    {
      int e = wave * 64 + lane;
      int row = e >> 2, kq = (e & 3) * 8;
      GLOAD_LDS16(Bb + (size_t)row * CKLEN + k0 + kq, Bs + wave * 512);
    }
    __syncthreads();
    v8s af[4], bfr[2];
#pragma unroll
    for (int i = 0; i < 4; ++i)
      af[i] = *(const v8s*)&As[(wm + i * 16 + lrow) * 32 + lquad * 8];
#pragma unroll
    for (int j = 0; j < 2; ++j)
      bfr[j] = *(const v8s*)&Bs[(wn + j * 16 + lrow) * 32 + lquad * 8];
#pragma unroll
    for (int i = 0; i < 4; ++i)
#pragma unroll
      for (int j = 0; j < 2; ++j)
        acc[i][j] = __builtin_amdgcn_mfma_f32_16x16x32_bf16(af[i], bfr[j], acc[i][j], 0, 0, 0);
  }

  float* outp = st + (size_t)(c * NH + h) * (HD * NSTATE);
#pragma unroll
  for (int i = 0; i < 4; ++i) {
    int p0 = wm + i * 16 + lquad * 4;
#pragma unroll
    for (int j = 0; j < 2; ++j) {
      int n = wn + j * 16 + lrow;
#pragma unroll
      for (int r = 0; r < 4; ++r)
        outp[(size_t)(p0 + r) * NSTATE + n] = acc[i][j][r];
    }
  }
}

// ---------------- inter-chunk scan -> bf16 sp ----------------
__global__ void scan_kernel(const float* __restrict__ acum,
                            const float* __restrict__ st,
                            unsigned short* __restrict__ spbf)
{
  int e = blockIdx.x * 256 + threadIdx.x;
  int h = e >> 13;
  float running = 0.f;
#pragma unroll
  for (int c = 0; c < NCHUNK; ++c) {
    spbf[(size_t)c * 262144 + e] = to_bf16(running);
    float dec = __expf(fminf(acum[h * L_SEQ + c * CKLEN + 255], 0.f));
    running = running * dec + st[(size_t)c * 262144 + e];
  }
}

// ---------------- Y v3: acc = Cbf @ sp^T; acc *= exp(Ac[l]);
//   acc += (mask . G . exp(Acl-Acs)) @ Xd^T computed ON THE FLY from fp32 G
//   (no Gexp materialization); Y = acc + D*xs ----------------
// 256 threads (4 waves): G-tile staging = 4 issues x 256thr x 16B = 16KB.
__global__ __launch_bounds__(256) void y_kernel_v3(
    const float* __restrict__ G, const unsigned short* __restrict__ Xd,
    const unsigned short* __restrict__ Cbf, const unsigned short* __restrict__ spbf,
    const float* __restrict__ xbc, const float* __restrict__ acum,
    const float* __restrict__ Dp, float* __restrict__ Y)
{
  const int b = blockIdx.x, h = blockIdx.y, c = blockIdx.z;
  const int tid = threadIdx.x;
  const int wave = tid >> 6, lane = tid & 63;
  const int wm = wave * 32;
  const int lrow = lane & 15, lquad = lane >> 4;

  __shared__ unsigned short As16[128 * 32];
  __shared__ unsigned short Bs[128 * 32];
  __shared__ float As32[128 * 32];        // 16KB fp32 G tile (swizzled layout)
  __shared__ float Acl[128];
  __shared__ float Acs[256];

  Acs[tid] = acum[h * L_SEQ + c * CKLEN + tid];
  if (tid < 128) Acl[tid] = acum[h * L_SEQ + c * CKLEN + b * 128 + tid];

  v4f acc[2][8] = {};

  // ---- state part: acc = Cbf @ sp^T ----
  const unsigned short* Ca = Cbf + (size_t)c * (CKLEN * NSTATE) + (size_t)b * 128 * NSTATE;
  const unsigned short* Sb = spbf + (size_t)(c * NH + h) * (HD * NSTATE);
  for (int n0 = 0; n0 < NSTATE; n0 += 32) {
    __syncthreads();
#pragma unroll
    for (int r = 0; r < 2; ++r) {
      int e = wave * 128 + r * 64 + lane;
      int row = e >> 2, kq = (e & 3) * 8;
      GLOAD_LDS16(Ca + (size_t)row * NSTATE + n0 + kq, As16 + wave * 1024 + r * 512);
      GLOAD_LDS16(Sb + (size_t)row * NSTATE + n0 + kq, Bs + wave * 1024 + r * 512);
    }
    __syncthreads();
    v8s af[2], bfr[8];
#pragma unroll
    for (int i = 0; i < 2; ++i)
      af[i] = *(const v8s*)&As16[(wm + i * 16 + lrow) * 32 + lquad * 8];
#pragma unroll
    for (int j = 0; j < 8; ++j)
      bfr[j] = *(const v8s*)&Bs[(j * 16 + lrow) * 32 + lquad * 8];
#pragma unroll
    for (int i = 0; i < 2; ++i)
#pragma unroll
      for (int j = 0; j < 8; ++j)
        acc[i][j] = __builtin_amdgcn_mfma_f32_16x16x32_bf16(af[i], bfr[j], acc[i][j], 0, 0, 0);
  }

  // ---- row-scale by per-head decay exp(Ac[l]) (from LDS) ----
#pragma unroll
  for (int i = 0; i < 2; ++i) {
#pragma unroll
    for (int r = 0; r < 4; ++r) {
      float eA = __expf(fminf(Acl[wm + i * 16 + lquad * 4 + r], 0.f));
#pragma unroll
      for (int j = 0; j < 8; ++j) acc[i][j][r] *= eA;
    }
  }

  // ---- diagonal part: acc += P @ Xd^T with P built on the fly from fp32 G ----
  const float* Gc = G + (size_t)c * 65536 + (size_t)b * 128 * 256;
  const unsigned short* Xb = Xd + (size_t)(c * NH + h) * (HD * CKLEN);

  const int smax = (b + 1) * 128;
  for (int s0 = 0; s0 < smax; s0 += 32) {
    __syncthreads();
    // stage 128x32 fp32 G tile (16KB = 4 issues x 256 thr x 16B),
    // pre-swizzled source, linear LDS dest (physical off == lin2)
#pragma unroll
    for (int g = 0; g < 4; ++g) {
      int lin2 = g * 4096 + tid * 16;
      int sw = lin2 ^ (((lin2 >> 7) & 7) << 4);
      int row = sw >> 7;                 // 0..127
      int c4  = (sw & 127) >> 2;         // fp32 col 0..31 (multiple of 4)
      GLOAD_LDS16(Gc + (size_t)row * 256 + s0 + c4,
                  (unsigned short*)((char*)As32 + g * 4096 + wave * 1024));
    }
#pragma unroll
    for (int r = 0; r < 2; ++r) {
      int e = wave * 128 + r * 64 + lane;
      int row = e >> 2, kq = (e & 3) * 8;
      GLOAD_LDS16(Xb + (size_t)row * CKLEN + s0 + kq, Bs + wave * 1024 + r * 512);
    }
    __syncthreads();
    if (s0 <= b * 128 + wm + 31) {    // causal wave skip
      v8s af[2], bfr[8];
#pragma unroll
      for (int i = 0; i < 2; ++i) {
        int rl = wm + i * 16 + lrow;         // local l-row 0..127
        float al = Acl[rl];
        int lg = b * 128 + rl;               // global-in-chunk l
        int byte0 = rl * 128 + lquad * 32;
        int b0 = byte0 ^ (((byte0 >> 7) & 7) << 4);
        int byte1 = byte0 + 16;
        int b1 = byte1 ^ (((byte1 >> 7) & 7) << 4);
        float4 ga = *(const float4*)((const char*)As32 + b0);
        float4 gb = *(const float4*)((const char*)As32 + b1);
        float gv[8] = {ga.x, ga.y, ga.z, ga.w, gb.x, gb.y, gb.z, gb.w};
        v8s a;
#pragma unroll
        for (int k = 0; k < 8; ++k) {
          int sg = s0 + lquad * 8 + k;
          float m = (sg <= lg) ? gv[k] * __expf(fminf(al - Acs[sg], 0.f)) : 0.f;
          a[k] = (short)to_bf16(m);
        }
        af[i] = a;
      }
#pragma unroll
      for (int j = 0; j < 8; ++j)
        bfr[j] = *(const v8s*)&Bs[(j * 16 + lrow) * 32 + lquad * 8];
#pragma unroll
      for (int i = 0; i < 2; ++i)
#pragma unroll
        for (int j = 0; j < 8; ++j)
          acc[i][j] = __builtin_amdgcn_mfma_f32_16x16x32_bf16(af[i], bfr[j], acc[i][j], 0, 0, 0);
    }
  }

  const float Dh = Dp[h];
#pragma unroll
  for (int i = 0; i < 2; ++i) {
#pragma unroll
    for (int j = 0; j < 8; ++j) {
      int p = j * 16 + lrow;
#pragma unroll
      for (int r = 0; r < 4; ++r) {
        int Lg = c * CKLEN + b * 128 + wm + i * 16 + lquad * 4 + r;
        float xs = xbc[(size_t)Lg * CONVD + h * HD + p];
        Y[(size_t)Lg * DIN + h * HD + p] = acc[i][j][r] + Dh * xs;
      }
    }
  }
}

// ---------------- gated RMSNorm -> bf16 ----------------
__global__ __launch_bounds__(256) void norm_gate_kernel(const float* __restrict__ Y,
                                                        const float* __restrict__ zx,
                                                        const float* __restrict__ nw,
                                                        unsigned short* __restrict__ gbf)
{
  int l = blockIdx.x;
  int t = threadIdx.x;
  float g[16];
  float ss = 0.f;
#pragma unroll
  for (int i = 0; i < 16; ++i) {
    int idx = i * 256 + t;
    float z = zx[(size_t)l * DPROJ + idx];
    float y = Y[(size_t)l * DIN + idx];
    float gv = y * (z / (1.f + __expf(-z)));
    g[i] = gv;
    ss += gv * gv;
  }
#pragma unroll
  for (int off = 32; off > 0; off >>= 1) ss += __shfl_down(ss, off);
  __shared__ float red[4];
  if ((t & 63) == 0) red[t >> 6] = ss;
  __syncthreads();
  float total = red[0] + red[1] + red[2] + red[3];
  float scale = rsqrtf(total / (float)DIN + 1e-5f);
#pragma unroll
  for (int i = 0; i < 16; ++i) {
    int idx = i * 256 + t;
    gbf[(size_t)l * DIN + idx] = to_bf16(g[i] * scale * nw[idx]);
  }
}

// ---------------- launch ----------------
extern "C" void kernel_launch(void* const* d_in, const int* in_sizes, int n_in,
                              void* d_out, int out_size, void* d_ws, size_t ws_size,
                              hipStream_t stream) {
  const float* x    = (const float*)d_in[0];
  const float* w1   = (const float*)d_in[1];
  const float* cw   = (const float*)d_in[2];
  const float* cb   = (const float*)d_in[3];
  const float* dtb  = (const float*)d_in[4];
  const float* alog = (const float*)d_in[5];
  const float* Dp   = (const float*)d_in[6];
  const float* nw   = (const float*)d_in[7];
  const float* w2   = (const float*)d_in[8];
  float* out = (float*)d_out;
  float* ws  = (float*)d_ws;

  // scratch layout (float units). Btw overlays w1bf region (dead after gemm1).
  // zx region reused for gemm2 split-K partials (zx dead after norm_gate).
  // st region doubles as gemm1-tail split-K partials (st written later).
  unsigned short* xbf  = (unsigned short*)(ws + 0);          // 2048*2048 bf16
  unsigned short* w1bf = (unsigned short*)(ws + 2097152);    // 8352*2048 bf16
  unsigned short* Btw  = (unsigned short*)(ws + 8388608);    // 8*32*64*256 bf16 (post-gemm1)
  unsigned short* w2bf = (unsigned short*)(ws + 10649600);   // 2048*4096 bf16
  float* zx   = ws + 14843904;   // 2048*8352
  float* part = ws + 14843904;   // 4*2048*2048 fp32 partials (post-norm_gate)
  float* xbc  = ws + 31948800;   // 2048*4224
  float* dt   = ws + 40599552;   // 2048*32
  float* acum = ws + 40665088;   // 32*2048
  float* G    = ws + 40730624;   // 8*256*256 fp32
  float* st   = ws + 41254912;   // 8*32*128*64 fp32 (also: 4*2048*160 tail partials, pre-states)
  float* Y    = ws + 43352064;   // 2048*4096
  unsigned short* gbf  = (unsigned short*)(ws + 51740672);   // 2048*4096 bf16
  unsigned short* Xd   = (unsigned short*)(ws + 53837824);   // 8*32*128*256 bf16
  unsigned short* Cbf  = (unsigned short*)(ws + 58032128);   // 8*256*64 bf16
  unsigned short* spbf = (unsigned short*)(ws + 58097664);   // 8*32*128*64 bf16

  cvt_bf16_kernel<<<4194304 / 2048, 256, 0, stream>>>(x, xbf, 4194304);
  cvt_bf16_kernel<<<17104896 / 2048, 256, 0, stream>>>(w1, w1bf, 17104896);
  cvt_bf16_kernel<<<8388608 / 2048, 256, 0, stream>>>(w2, w2bf, 8388608);

  // zxbcdt = x @ in_proj_w^T   (M=2048, N=8352, K=2048)
  // main: 256x256 8-phase + XCD swizzle on cols 0..8191 (256 blocks, 1 round)
  gemm_nt_256<<<dim3(8, 32, 1), 512, 0, stream>>>(
      xbf, w1bf, zx, 2048, 2048, 8352, 8352, 2048);
  // tail: cols 8192..8351 (160 cols), split-K x4 (256 blocks) -> st scratch
  gemm_nt_64tail<<<dim3(32, 2, 4), 256, 0, stream>>>(
      xbf, w1bf + (size_t)8192 * 2048, st, 160, 160, 2048, 512);
  reduce_tail_kernel<<<320, 256, 0, stream>>>(st, zx + 8192);

  conv_silu_kernel<<<dim3(64, 33), 256, 0, stream>>>(zx, cw, cb, xbc);
  dt_kernel<<<(L_SEQ * NH) / 256, 256, 0, stream>>>(zx, dtb, dt);
  acum_kernel<<<NCHUNK * NH, 256, 0, stream>>>(dt, alog, acum);

  prep_kernel<<<NCHUNK * NH, 256, 0, stream>>>(xbc, dt, acum, Xd, Btw, Cbf);
  g_kernel<<<dim3(4, 4, NCHUNK), 256, 0, stream>>>(xbc, G);

  states_kernel_v2<<<NCHUNK * NH, 256, 0, stream>>>(Xd, Btw, st);
  scan_kernel<<<262144 / 256, 256, 0, stream>>>(acum, st, spbf);
  y_kernel_v3<<<dim3(2, NH, NCHUNK), 256, 0, stream>>>(G, Xd, Cbf, spbf, xbc, acum, Dp, Y);

  norm_gate_kernel<<<L_SEQ, 256, 0, stream>>>(Y, zx, nw, gbf);

  // out = g @ out_proj_w^T (M=2048, N=2048, K=4096): split-K x4 through the
  // 256x256 8-phase kernel (grid 8x8x4 = 256 blocks, K=1024/split), fp32
  // partials in the dead zx region, then a float4 reduce.
  gemm_nt_256<<<dim3(8, 8, 4), 512, 0, stream>>>(
      gbf, w2bf, part, 4096, 4096, 2048, 2048, 1024);
  reduce_k4_kernel<<<4194304 / 1024, 256, 0, stream>>>(part, out, 4194304);
}